// Round 1
// baseline (12891.988 us; speedup 1.0000x reference)
//
#include <hip/hip_runtime.h>
#include <math.h>

#define NN  50000
#define NE  400000
#define NTE 50000
#define FIN 64
#define EDIM 32
#define HD  128
#define NL  2

static __device__ __forceinline__ unsigned fenc(float f) {
    unsigned u = __float_as_uint(f);
    return (u & 0x80000000u) ? ~u : (u | 0x80000000u);
}
static __device__ __forceinline__ float fdec(unsigned u) {
    return (u & 0x80000000u) ? __uint_as_float(u & 0x7fffffffu) : __uint_as_float(~u);
}

// ---- generic GEMM: C[M x 128] = A[M x K] @ W[K x 128] (+bias). In-place (C==A) safe. ----
template<int K>
__global__ void __launch_bounds__(256) k_gemm_rm(const float* A, const float* __restrict__ W,
                                                 const float* __restrict__ bias, float* C, int M)
{
    __shared__ float T[K][68];
    const int t = threadIdx.x;
    const int row0 = blockIdx.x * 64;
    {
        const int r = t & 63, q = t >> 6;
        const int grow = row0 + r;
        const bool ok = grow < M;
        const float* p = A + (size_t)grow * K + q * (K / 4);
        #pragma unroll
        for (int kk = 0; kk < K / 16; ++kk) {
            float4 v = ok ? *(const float4*)(p + kk * 4) : make_float4(0.f, 0.f, 0.f, 0.f);
            const int k = q * (K / 4) + kk * 4;
            T[k + 0][r] = v.x; T[k + 1][r] = v.y; T[k + 2][r] = v.z; T[k + 3][r] = v.w;
        }
    }
    __syncthreads();
    const int cg = t & 15, rg = t >> 4;
    const int c0 = cg * 8, r0 = rg * 4;
    float acc[4][8] = {};
    #pragma unroll 8
    for (int k = 0; k < K; ++k) {
        const float4 a  = *(const float4*)&T[k][r0];
        const float4 w0 = *(const float4*)(W + (size_t)k * HD + c0);
        const float4 w1 = *(const float4*)(W + (size_t)k * HD + c0 + 4);
        const float av[4] = {a.x, a.y, a.z, a.w};
        const float wv[8] = {w0.x, w0.y, w0.z, w0.w, w1.x, w1.y, w1.z, w1.w};
        #pragma unroll
        for (int i = 0; i < 4; ++i)
            #pragma unroll
            for (int j = 0; j < 8; ++j)
                acc[i][j] += av[i] * wv[j];
    }
    float bv[8];
    #pragma unroll
    for (int j = 0; j < 8; ++j) bv[j] = bias ? bias[c0 + j] : 0.f;
    #pragma unroll
    for (int i = 0; i < 4; ++i) {
        const int grow = row0 + r0 + i;
        if (grow < M) {
            float4 o0 = make_float4(acc[i][0]+bv[0], acc[i][1]+bv[1], acc[i][2]+bv[2], acc[i][3]+bv[3]);
            float4 o1 = make_float4(acc[i][4]+bv[4], acc[i][5]+bv[5], acc[i][6]+bv[6], acc[i][7]+bv[7]);
            *(float4*)(C + (size_t)grow * HD + c0)     = o0;
            *(float4*)(C + (size_t)grow * HD + c0 + 4) = o1;
        }
    }
}

// ---- degree count ----
__global__ void __launch_bounds__(256) k_count(const int* __restrict__ d, int* __restrict__ cnt, int E)
{
    const int e = blockIdx.x * 256 + threadIdx.x;
    if (e < E) atomicAdd(&cnt[d[e]], 1);
}

// ---- mean(log(cnt+1)) numerator ----
__global__ void __launch_bounds__(256) k_avglog(const int* __restrict__ cnt, float* __restrict__ stats)
{
    float s = 0.f;
    for (int n = blockIdx.x * 256 + threadIdx.x; n < NN; n += gridDim.x * 256)
        s += logf((float)cnt[n] + 1.f);
    #pragma unroll
    for (int off = 32; off > 0; off >>= 1) s += __shfl_down(s, off);
    __shared__ float ls[4];
    if ((threadIdx.x & 63) == 0) ls[threadIdx.x >> 6] = s;
    __syncthreads();
    if (threadIdx.x == 0) unsafeAtomicAdd(stats, ls[0] + ls[1] + ls[2] + ls[3]);
}

// ---- fused: m = ea@We + xd[dst] + xs[src]  (bias folded into xd); atomic agg into sum/sq/min/max ----
__global__ void __launch_bounds__(256) k_msg_agg(const float* __restrict__ ea,
        const float* __restrict__ We, const float* __restrict__ xd, const float* __restrict__ xs,
        const int* __restrict__ srcp, const int* __restrict__ dstp,
        float* __restrict__ asum, float* __restrict__ asq,
        unsigned* __restrict__ amn, unsigned* __restrict__ amx, int E)
{
    __shared__ float T[HD][68];
    __shared__ int s_src[64], s_dst[64];
    const int t = threadIdx.x;
    const int row0 = blockIdx.x * 64;
    if (t < 64) {
        const int e = row0 + t;
        s_src[t] = (e < E) ? srcp[e] : 0;
        s_dst[t] = (e < E) ? dstp[e] : 0;
    }
    {
        const int r = t & 63, q = t >> 6;
        const int e = row0 + r;
        const bool ok = e < E;
        const float* p = ea + (size_t)e * HD + q * 32;
        #pragma unroll
        for (int kk = 0; kk < 8; ++kk) {
            float4 v = ok ? *(const float4*)(p + kk * 4) : make_float4(0.f,0.f,0.f,0.f);
            const int k = q * 32 + kk * 4;
            T[k+0][r]=v.x; T[k+1][r]=v.y; T[k+2][r]=v.z; T[k+3][r]=v.w;
        }
    }
    __syncthreads();
    const int cg = t & 15, rg = t >> 4;
    const int c0 = cg * 8, r0 = rg * 4;
    float acc[4][8] = {};
    #pragma unroll 8
    for (int k = 0; k < HD; ++k) {
        const float4 a  = *(const float4*)&T[k][r0];
        const float4 w0 = *(const float4*)(We + (size_t)k * HD + c0);
        const float4 w1 = *(const float4*)(We + (size_t)k * HD + c0 + 4);
        const float av[4] = {a.x, a.y, a.z, a.w};
        const float wv[8] = {w0.x, w0.y, w0.z, w0.w, w1.x, w1.y, w1.z, w1.w};
        #pragma unroll
        for (int i = 0; i < 4; ++i)
            #pragma unroll
            for (int j = 0; j < 8; ++j)
                acc[i][j] += av[i] * wv[j];
    }
    #pragma unroll
    for (int i = 0; i < 4; ++i) {
        const int e = row0 + r0 + i;
        if (e >= E) continue;
        const int dn = s_dst[r0 + i], sn = s_src[r0 + i];
        const float* pd = xd + (size_t)dn * HD + c0;
        const float* ps = xs + (size_t)sn * HD + c0;
        const float4 d0 = *(const float4*)pd, d1 = *(const float4*)(pd + 4);
        const float4 s0 = *(const float4*)ps, s1 = *(const float4*)(ps + 4);
        const float dv[8] = {d0.x,d0.y,d0.z,d0.w,d1.x,d1.y,d1.z,d1.w};
        const float sv[8] = {s0.x,s0.y,s0.z,s0.w,s1.x,s1.y,s1.z,s1.w};
        float*    psum = asum + (size_t)dn * HD + c0;
        float*    psq  = asq  + (size_t)dn * HD + c0;
        unsigned* pmn  = amn  + (size_t)dn * HD + c0;
        unsigned* pmx  = amx  + (size_t)dn * HD + c0;
        #pragma unroll
        for (int j = 0; j < 8; ++j) {
            const float m = acc[i][j] + dv[j] + sv[j];
            unsafeAtomicAdd(psum + j, m);
            unsafeAtomicAdd(psq + j, m * m);
            const unsigned u = fenc(m);
            atomicMax(pmx + j, u);
            atomicMin(pmn + j, u);
        }
    }
}

// ---- post: out = x@B0 + sum_j aggj@B(1+j) + amp*sum_j aggj@B(5+j) + att*sum_j aggj@B(9+j) + pb ----
__global__ void __launch_bounds__(256) k_post(const float* __restrict__ x,
        const float* __restrict__ asum, const float* __restrict__ asq,
        const unsigned* __restrict__ amn, const unsigned* __restrict__ amx,
        const int* __restrict__ cnt, const float* __restrict__ stats,
        const float* __restrict__ PW, const float* __restrict__ pb,
        float* __restrict__ outb, int M)
{
    __shared__ float T[HD][68];
    __shared__ float s_cnt[64];
    const int t = threadIdx.x;
    const int row0 = blockIdx.x * 64;
    if (t < 64) {
        const int n = row0 + t;
        s_cnt[t] = (n < M) ? (float)cnt[n] : 0.f;
    }
    const int r = t & 63, q = t >> 6;
    const int nrow = row0 + r;
    const bool ok = nrow < M;
    const int cg = t & 15, rg = t >> 4;
    const int c0 = cg * 8, r0 = rg * 4;
    float accA[4][8] = {}, accB[4][8] = {}, accC[4][8] = {};

    // phase X: x @ PW[0:128]
    {
        const float* p = x + (size_t)nrow * HD + q * 32;
        #pragma unroll
        for (int kk = 0; kk < 8; ++kk) {
            float4 v = ok ? *(const float4*)(p + kk * 4) : make_float4(0.f,0.f,0.f,0.f);
            const int k = q * 32 + kk * 4;
            T[k+0][r]=v.x; T[k+1][r]=v.y; T[k+2][r]=v.z; T[k+3][r]=v.w;
        }
    }
    __syncthreads();
    #pragma unroll 4
    for (int k = 0; k < HD; ++k) {
        const float4 a  = *(const float4*)&T[k][r0];
        const float4 w0 = *(const float4*)(PW + (size_t)k * HD + c0);
        const float4 w1 = *(const float4*)(PW + (size_t)k * HD + c0 + 4);
        const float av[4] = {a.x, a.y, a.z, a.w};
        const float wv[8] = {w0.x, w0.y, w0.z, w0.w, w1.x, w1.y, w1.z, w1.w};
        #pragma unroll
        for (int i = 0; i < 4; ++i)
            #pragma unroll
            for (int j = 0; j < 8; ++j)
                accA[i][j] += av[i] * wv[j];
    }

    const float cf  = s_cnt[r];
    const float inv = 1.f / fmaxf(cf, 1.f);
    const bool  has = cf > 0.f;
    const size_t base = (size_t)nrow * HD + q * 32;

    for (int jb = 0; jb < 4; ++jb) {
        __syncthreads();
        #pragma unroll
        for (int kk = 0; kk < 8; ++kk) {
            const int k = q * 32 + kk * 4;
            float v[4];
            if (!ok) { v[0]=v[1]=v[2]=v[3]=0.f; }
            else if (jb == 0) {
                const float4 sv = *(const float4*)(asum + base + kk * 4);
                v[0]=sv.x*inv; v[1]=sv.y*inv; v[2]=sv.z*inv; v[3]=sv.w*inv;
            } else if (jb == 1) {
                const uint4 uv = *(const uint4*)(amn + base + kk * 4);
                v[0]=has?fdec(uv.x):0.f; v[1]=has?fdec(uv.y):0.f;
                v[2]=has?fdec(uv.z):0.f; v[3]=has?fdec(uv.w):0.f;
            } else if (jb == 2) {
                const uint4 uv = *(const uint4*)(amx + base + kk * 4);
                v[0]=has?fdec(uv.x):0.f; v[1]=has?fdec(uv.y):0.f;
                v[2]=has?fdec(uv.z):0.f; v[3]=has?fdec(uv.w):0.f;
            } else {
                const float4 sv = *(const float4*)(asum + base + kk * 4);
                const float4 qv = *(const float4*)(asq  + base + kk * 4);
                const float m0=sv.x*inv, m1=sv.y*inv, m2=sv.z*inv, m3=sv.w*inv;
                v[0]=sqrtf(fmaxf(qv.x*inv - m0*m0, 0.f) + 1e-5f);
                v[1]=sqrtf(fmaxf(qv.y*inv - m1*m1, 0.f) + 1e-5f);
                v[2]=sqrtf(fmaxf(qv.z*inv - m2*m2, 0.f) + 1e-5f);
                v[3]=sqrtf(fmaxf(qv.w*inv - m3*m3, 0.f) + 1e-5f);
            }
            T[k+0][r]=v[0]; T[k+1][r]=v[1]; T[k+2][r]=v[2]; T[k+3][r]=v[3];
        }
        __syncthreads();
        const float* W1 = PW + (size_t)(128  + jb * 128) * HD;
        const float* W2 = PW + (size_t)(640  + jb * 128) * HD;
        const float* W3 = PW + (size_t)(1152 + jb * 128) * HD;
        #pragma unroll 4
        for (int k = 0; k < HD; ++k) {
            const float4 a = *(const float4*)&T[k][r0];
            const float av[4] = {a.x, a.y, a.z, a.w};
            const float4 u0 = *(const float4*)(W1 + (size_t)k*HD + c0), u1 = *(const float4*)(W1 + (size_t)k*HD + c0 + 4);
            const float4 v0 = *(const float4*)(W2 + (size_t)k*HD + c0), v1 = *(const float4*)(W2 + (size_t)k*HD + c0 + 4);
            const float4 t0 = *(const float4*)(W3 + (size_t)k*HD + c0), t1 = *(const float4*)(W3 + (size_t)k*HD + c0 + 4);
            const float w1v[8] = {u0.x,u0.y,u0.z,u0.w,u1.x,u1.y,u1.z,u1.w};
            const float w2v[8] = {v0.x,v0.y,v0.z,v0.w,v1.x,v1.y,v1.z,v1.w};
            const float w3v[8] = {t0.x,t0.y,t0.z,t0.w,t1.x,t1.y,t1.z,t1.w};
            #pragma unroll
            for (int i = 0; i < 4; ++i)
                #pragma unroll
                for (int j = 0; j < 8; ++j) {
                    accA[i][j] += av[i] * w1v[j];
                    accB[i][j] += av[i] * w2v[j];
                    accC[i][j] += av[i] * w3v[j];
                }
        }
    }
    const float avg = stats[0] * (1.f / (float)NN);
    float bv[8];
    #pragma unroll
    for (int j = 0; j < 8; ++j) bv[j] = pb[c0 + j];
    #pragma unroll
    for (int i = 0; i < 4; ++i) {
        const int n = row0 + r0 + i;
        if (n >= M) continue;
        const float c  = s_cnt[r0 + i];
        const float lg = logf(fmaxf(c, 1.f) + 1.f);
        const float amp = lg / avg, att = avg / lg;
        float o[8];
        #pragma unroll
        for (int j = 0; j < 8; ++j)
            o[j] = accA[i][j] + amp * accB[i][j] + att * accC[i][j] + bv[j];
        *(float4*)(outb + (size_t)n * HD + c0)     = make_float4(o[0],o[1],o[2],o[3]);
        *(float4*)(outb + (size_t)n * HD + c0 + 4) = make_float4(o[4],o[5],o[6],o[7]);
    }
}

// ---- BN column sums ----
__global__ void __launch_bounds__(256) k_bnstats(const float* __restrict__ ob,
        float* __restrict__ bs, float* __restrict__ bq, int M)
{
    const int c = threadIdx.x & 127;
    const int gsub = threadIdx.x >> 7;
    float s = 0.f, qq = 0.f;
    for (int rr = blockIdx.x * 2 + gsub; rr < M; rr += gridDim.x * 2) {
        const float v = ob[(size_t)rr * HD + c];
        s += v; qq += v * v;
    }
    __shared__ float ls[2][HD], lq[2][HD];
    ls[gsub][c] = s; lq[gsub][c] = qq;
    __syncthreads();
    if (gsub == 0) {
        unsafeAtomicAdd(&bs[c], ls[0][c] + ls[1][c]);
        unsafeAtomicAdd(&bq[c], lq[0][c] + lq[1][c]);
    }
}

// ---- x = (x + relu(bn(out)))/2 ----
__global__ void __launch_bounds__(256) k_xupdate(float* x, const float* __restrict__ ob,
        const float* __restrict__ bs, const float* __restrict__ bq,
        const float* __restrict__ g, const float* __restrict__ bb)
{
    const int i = blockIdx.x * 256 + threadIdx.x;   // float4 index; grid sized exactly
    const int c0 = (i & 31) * 4;
    const float4 ov = ((const float4*)ob)[i];
    const float4 xv = ((const float4*)x)[i];
    const float o[4]  = {ov.x, ov.y, ov.z, ov.w};
    const float xo[4] = {xv.x, xv.y, xv.z, xv.w};
    float res[4];
    #pragma unroll
    for (int j = 0; j < 4; ++j) {
        const int c = c0 + j;
        const float mu  = bs[c] * (1.f / (float)NN);
        const float var = bq[c] * (1.f / (float)NN) - mu * mu;
        const float bn  = g[c] * (o[j] - mu) * rsqrtf(var + 1e-5f) + bb[c];
        res[j] = (xo[j] + fmaxf(bn, 0.f)) * 0.5f;
    }
    ((float4*)x)[i] = make_float4(res[0], res[1], res[2], res[3]);
}

// ---- edge update: hid = relu(ea@W1e + xs1[src] + xd1[dst]); ea += (hid@em2 + e2b)/2 ----
__global__ void __launch_bounds__(256) k_edge_upd(float* ea, const float* __restrict__ W1e,
        const float* __restrict__ e2W, const float* __restrict__ e2b,
        const float* __restrict__ xs1, const float* __restrict__ xd1,
        const int* __restrict__ srcp, const int* __restrict__ dstp, int E)
{
    __shared__ float T[HD][68];
    __shared__ int s_src[64], s_dst[64];
    const int t = threadIdx.x;
    const int row0 = blockIdx.x * 64;
    if (t < 64) {
        const int e = row0 + t;
        s_src[t] = (e < E) ? srcp[e] : 0;
        s_dst[t] = (e < E) ? dstp[e] : 0;
    }
    {
        const int r = t & 63, q = t >> 6;
        const int e = row0 + r;
        const bool ok = e < E;
        const float* p = ea + (size_t)e * HD + q * 32;
        #pragma unroll
        for (int kk = 0; kk < 8; ++kk) {
            float4 v = ok ? *(const float4*)(p + kk * 4) : make_float4(0.f,0.f,0.f,0.f);
            const int k = q * 32 + kk * 4;
            T[k+0][r]=v.x; T[k+1][r]=v.y; T[k+2][r]=v.z; T[k+3][r]=v.w;
        }
    }
    __syncthreads();
    const int cg = t & 15, rg = t >> 4;
    const int c0 = cg * 8, r0 = rg * 4;
    float acc[4][8] = {};
    #pragma unroll 8
    for (int k = 0; k < HD; ++k) {
        const float4 a  = *(const float4*)&T[k][r0];
        const float4 w0 = *(const float4*)(W1e + (size_t)k * HD + c0);
        const float4 w1 = *(const float4*)(W1e + (size_t)k * HD + c0 + 4);
        const float av[4] = {a.x, a.y, a.z, a.w};
        const float wv[8] = {w0.x, w0.y, w0.z, w0.w, w1.x, w1.y, w1.z, w1.w};
        #pragma unroll
        for (int i = 0; i < 4; ++i)
            #pragma unroll
            for (int j = 0; j < 8; ++j)
                acc[i][j] += av[i] * wv[j];
    }
    // save own ea tile, compute hid
    float eaold[4][8], hid[4][8];
    #pragma unroll
    for (int i = 0; i < 4; ++i) {
        #pragma unroll
        for (int j = 0; j < 8; ++j) eaold[i][j] = T[c0 + j][r0 + i];
        const int sn = s_src[r0 + i], dn = s_dst[r0 + i];
        const float* ps = xs1 + (size_t)sn * HD + c0;
        const float* pd = xd1 + (size_t)dn * HD + c0;
        const float4 s0 = *(const float4*)ps, s1 = *(const float4*)(ps + 4);
        const float4 d0 = *(const float4*)pd, d1 = *(const float4*)(pd + 4);
        const float sv[8] = {s0.x,s0.y,s0.z,s0.w,s1.x,s1.y,s1.z,s1.w};
        const float dv[8] = {d0.x,d0.y,d0.z,d0.w,d1.x,d1.y,d1.z,d1.w};
        #pragma unroll
        for (int j = 0; j < 8; ++j)
            hid[i][j] = fmaxf(acc[i][j] + sv[j] + dv[j], 0.f);
    }
    __syncthreads();            // all reads of T (gemm1 + eaold) complete
    #pragma unroll
    for (int i = 0; i < 4; ++i)
        #pragma unroll
        for (int j = 0; j < 8; ++j)
            T[c0 + j][r0 + i] = hid[i][j];
    __syncthreads();
    float acc2[4][8] = {};
    #pragma unroll 8
    for (int k = 0; k < HD; ++k) {
        const float4 a  = *(const float4*)&T[k][r0];
        const float4 w0 = *(const float4*)(e2W + (size_t)k * HD + c0);
        const float4 w1 = *(const float4*)(e2W + (size_t)k * HD + c0 + 4);
        const float av[4] = {a.x, a.y, a.z, a.w};
        const float wv[8] = {w0.x, w0.y, w0.z, w0.w, w1.x, w1.y, w1.z, w1.w};
        #pragma unroll
        for (int i = 0; i < 4; ++i)
            #pragma unroll
            for (int j = 0; j < 8; ++j)
                acc2[i][j] += av[i] * wv[j];
    }
    float bv[8];
    #pragma unroll
    for (int j = 0; j < 8; ++j) bv[j] = e2b[c0 + j];
    #pragma unroll
    for (int i = 0; i < 4; ++i) {
        const int e = row0 + r0 + i;
        if (e >= E) continue;
        float o[8];
        #pragma unroll
        for (int j = 0; j < 8; ++j)
            o[j] = eaold[i][j] + (acc2[i][j] + bv[j]) * 0.5f;
        *(float4*)(ea + (size_t)e * HD + c0)     = make_float4(o[0],o[1],o[2],o[3]);
        *(float4*)(ea + (size_t)e * HD + c0 + 4) = make_float4(o[4],o[5],o[6],o[7]);
    }
}

extern "C" void kernel_launch(void* const* d_in, const int* in_sizes, int n_in,
                              void* d_out, int out_size, void* d_ws, size_t ws_size,
                              hipStream_t stream)
{
    const float* x0    = (const float*)d_in[0];
    const float* eatr  = (const float*)d_in[1];
    const float* teatr = (const float*)d_in[2];
    const float* nodeW = (const float*)d_in[3];
    const float* nodeb = (const float*)d_in[4];
    const float* edgeW = (const float*)d_in[5];
    const float* edgeb = (const float*)d_in[6];
    const float* preW  = (const float*)d_in[7];
    const float* preb  = (const float*)d_in[8];
    const float* postW = (const float*)d_in[9];
    const float* postb = (const float*)d_in[10];
    const float* linW  = (const float*)d_in[11];
    const float* linb  = (const float*)d_in[12];
    const float* bng   = (const float*)d_in[13];
    const float* bnb   = (const float*)d_in[14];
    const float* em1W  = (const float*)d_in[15];
    const float* em1b  = (const float*)d_in[16];
    const float* em2W  = (const float*)d_in[17];
    const float* em2b  = (const float*)d_in[18];
    const int*   eidx  = (const int*)d_in[19];
    const int* srcp = eidx;
    const int* dstp = eidx + NE;

    float* out_x  = (float*)d_out;
    float* out_ea = out_x + (size_t)NN * HD;
    float* out_te = out_ea + (size_t)NE * HD;

    const size_t NH = (size_t)NN * HD;
    float* xd   = (float*)d_ws;
    float* xs   = xd + NH;
    float* asum = xs + NH;
    float* asq  = asum + NH;
    unsigned* amn = (unsigned*)(asq + NH);
    unsigned* amx = amn + NH;
    float* outb = (float*)(amx + NH);
    int*   cnt  = (int*)(outb + NH);
    float* stats = (float*)(cnt + NN);  // [0]=sum log; [128..255]=bn sum; [256..383]=bn sumsq

    hipMemsetAsync(cnt, 0, NN * sizeof(int), stream);
    hipMemsetAsync(stats, 0, 512 * sizeof(float), stream);

    k_gemm_rm<EDIM><<<(NE + 63) / 64, 256, 0, stream>>>(eatr, edgeW, edgeb, out_ea, NE);
    k_gemm_rm<EDIM><<<(NTE + 63) / 64, 256, 0, stream>>>(teatr, edgeW, edgeb, out_te, NTE);
    k_gemm_rm<FIN><<<(NN + 63) / 64, 256, 0, stream>>>(x0, nodeW, nodeb, out_x, NN);
    k_count<<<(NE + 255) / 256, 256, 0, stream>>>(dstp, cnt, NE);
    k_avglog<<<256, 256, 0, stream>>>(cnt, stats);

    const int gn = (NN + 63) / 64;
    const int ge = (NE + 63) / 64;

    for (int l = 0; l < NL; ++l) {
        const float* Wd  = preW + (size_t)l * 384 * HD;
        const float* Ws_ = Wd + 128 * HD;
        const float* We  = Wd + 256 * HD;
        const float* pbl = preb + l * HD;
        const float* PW  = postW + (size_t)l * 1664 * HD;
        const float* pob = postb + l * HD;
        const float* lW  = linW + (size_t)l * HD * HD;
        const float* lb  = linb + l * HD;
        const float* g_  = bng + l * HD;
        const float* b_  = bnb + l * HD;
        const float* W1s = em1W + (size_t)l * 384 * HD;
        const float* W1d = W1s + 128 * HD;
        const float* W1e = W1s + 256 * HD;
        const float* e1b = em1b + l * HD;
        const float* e2W = em2W + (size_t)l * HD * HD;
        const float* e2b = em2b + l * HD;

        hipMemsetAsync(asum, 0, NH * sizeof(float), stream);
        hipMemsetAsync(asq,  0, NH * sizeof(float), stream);
        hipMemsetAsync(amn, 0xFF, NH * sizeof(unsigned), stream);
        hipMemsetAsync(amx, 0x00, NH * sizeof(unsigned), stream);
        hipMemsetAsync(stats + 128, 0, 256 * sizeof(float), stream);

        k_gemm_rm<HD><<<gn, 256, 0, stream>>>(out_x, Wd, pbl, xd, NN);
        k_gemm_rm<HD><<<gn, 256, 0, stream>>>(out_x, Ws_, nullptr, xs, NN);
        k_msg_agg<<<ge, 256, 0, stream>>>(out_ea, We, xd, xs, srcp, dstp, asum, asq, amn, amx, NE);
        k_post<<<gn, 256, 0, stream>>>(out_x, asum, asq, amn, amx, cnt, stats, PW, pob, outb, NN);
        k_gemm_rm<HD><<<gn, 256, 0, stream>>>(outb, lW, lb, outb, NN);   // in-place lin
        k_bnstats<<<256, 256, 0, stream>>>(outb, stats + 128, stats + 256, NN);
        k_xupdate<<<NN * 32 / 256, 256, 0, stream>>>(out_x, outb, stats + 128, stats + 256, g_, b_);
        k_gemm_rm<HD><<<gn, 256, 0, stream>>>(out_x, W1s, nullptr, xs, NN);   // xs1
        k_gemm_rm<HD><<<gn, 256, 0, stream>>>(out_x, W1d, e1b, xd, NN);       // xd1 (+em1_b)
        k_edge_upd<<<ge, 256, 0, stream>>>(out_ea, W1e, e2W, e2b, xs, xd, srcp, dstp, NE);
    }
}

// Round 2
// 4836.385 us; speedup vs baseline: 2.6656x; 2.6656x over previous
//
#include <hip/hip_runtime.h>
#include <math.h>

#define NN  50000
#define NE  400000
#define NTE 50000
#define FIN 64
#define EDIM 32
#define HD  128
#define NL  2
#define SCAN_B ((NN + 255) / 256)

// ---- generic GEMM: C[M x 128] = A[M x K] @ W[K x 128] (+bias). In-place (C==A) safe. ----
template<int K>
__global__ void __launch_bounds__(256) k_gemm_rm(const float* A, const float* __restrict__ W,
                                                 const float* __restrict__ bias, float* C, int M)
{
    __shared__ float T[K][68];
    const int t = threadIdx.x;
    const int row0 = blockIdx.x * 64;
    {
        const int r = t & 63, q = t >> 6;
        const int grow = row0 + r;
        const bool ok = grow < M;
        const float* p = A + (size_t)grow * K + q * (K / 4);
        #pragma unroll
        for (int kk = 0; kk < K / 16; ++kk) {
            float4 v = ok ? *(const float4*)(p + kk * 4) : make_float4(0.f, 0.f, 0.f, 0.f);
            const int k = q * (K / 4) + kk * 4;
            T[k + 0][r] = v.x; T[k + 1][r] = v.y; T[k + 2][r] = v.z; T[k + 3][r] = v.w;
        }
    }
    __syncthreads();
    const int cg = t & 15, rg = t >> 4;
    const int c0 = cg * 8, r0 = rg * 4;
    float acc[4][8] = {};
    #pragma unroll 8
    for (int k = 0; k < K; ++k) {
        const float4 a  = *(const float4*)&T[k][r0];
        const float4 w0 = *(const float4*)(W + (size_t)k * HD + c0);
        const float4 w1 = *(const float4*)(W + (size_t)k * HD + c0 + 4);
        const float av[4] = {a.x, a.y, a.z, a.w};
        const float wv[8] = {w0.x, w0.y, w0.z, w0.w, w1.x, w1.y, w1.z, w1.w};
        #pragma unroll
        for (int i = 0; i < 4; ++i)
            #pragma unroll
            for (int j = 0; j < 8; ++j)
                acc[i][j] += av[i] * wv[j];
    }
    float bv[8];
    #pragma unroll
    for (int j = 0; j < 8; ++j) bv[j] = bias ? bias[c0 + j] : 0.f;
    #pragma unroll
    for (int i = 0; i < 4; ++i) {
        const int grow = row0 + r0 + i;
        if (grow < M) {
            float4 o0 = make_float4(acc[i][0]+bv[0], acc[i][1]+bv[1], acc[i][2]+bv[2], acc[i][3]+bv[3]);
            float4 o1 = make_float4(acc[i][4]+bv[4], acc[i][5]+bv[5], acc[i][6]+bv[6], acc[i][7]+bv[7]);
            *(float4*)(C + (size_t)grow * HD + c0)     = o0;
            *(float4*)(C + (size_t)grow * HD + c0 + 4) = o1;
        }
    }
}

// ---- degree count ----
__global__ void __launch_bounds__(256) k_count(const int* __restrict__ d, int* __restrict__ cnt, int E)
{
    const int e = blockIdx.x * 256 + threadIdx.x;
    if (e < E) atomicAdd(&cnt[d[e]], 1);
}

// ---- mean(log(cnt+1)) numerator ----
__global__ void __launch_bounds__(256) k_avglog(const int* __restrict__ cnt, float* __restrict__ stats)
{
    float s = 0.f;
    for (int n = blockIdx.x * 256 + threadIdx.x; n < NN; n += gridDim.x * 256)
        s += logf((float)cnt[n] + 1.f);
    #pragma unroll
    for (int off = 32; off > 0; off >>= 1) s += __shfl_down(s, off);
    __shared__ float ls[4];
    if ((threadIdx.x & 63) == 0) ls[threadIdx.x >> 6] = s;
    __syncthreads();
    if (threadIdx.x == 0) unsafeAtomicAdd(stats, ls[0] + ls[1] + ls[2] + ls[3]);
}

// ---- CSR build: block inclusive scan ----
__global__ void __launch_bounds__(256) k_scan_block(const int* __restrict__ cnt,
        int* __restrict__ incl, int* __restrict__ part)
{
    __shared__ int s[256];
    const int t = threadIdx.x;
    const int i = blockIdx.x * 256 + t;
    const int v = (i < NN) ? cnt[i] : 0;
    s[t] = v;
    __syncthreads();
    #pragma unroll
    for (int off = 1; off < 256; off <<= 1) {
        const int x = (t >= off) ? s[t - off] : 0;
        __syncthreads();
        s[t] += x;
        __syncthreads();
    }
    if (i < NN) incl[i] = s[t];
    if (t == 255) part[blockIdx.x] = s[255];
}

__global__ void __launch_bounds__(256) k_scan_part(const int* __restrict__ part,
        int* __restrict__ poff, int np)
{
    __shared__ int s[256];
    const int t = threadIdx.x;
    const int v = (t < np) ? part[t] : 0;
    s[t] = v;
    __syncthreads();
    #pragma unroll
    for (int off = 1; off < 256; off <<= 1) {
        const int x = (t >= off) ? s[t - off] : 0;
        __syncthreads();
        s[t] += x;
        __syncthreads();
    }
    poff[t] = s[t] - v;  // exclusive
}

__global__ void __launch_bounds__(256) k_scan_add(const int* __restrict__ incl,
        const int* __restrict__ cnt, const int* __restrict__ poff,
        int* __restrict__ row_start, int* __restrict__ cursor)
{
    const int i = blockIdx.x * 256 + threadIdx.x;
    if (i < NN) {
        const int excl = incl[i] - cnt[i] + poff[blockIdx.x];
        row_start[i] = excl;
        cursor[i] = excl;
    }
    if (i == 0) row_start[NN] = NE;
}

__global__ void __launch_bounds__(256) k_scatter(const int* __restrict__ dstp,
        int* cursor, int* __restrict__ sppos)
{
    const int e = blockIdx.x * 256 + threadIdx.x;
    if (e < NE) sppos[e] = atomicAdd(&cursor[dstp[e]], 1);
}

// ---- fused: m = ea@We + xd[dst] + xs[src] (bias folded into xd); row-scatter into mbuf[sppos] ----
__global__ void __launch_bounds__(256) k_msg(const float* __restrict__ ea,
        const float* __restrict__ We, const float* __restrict__ xd, const float* __restrict__ xs,
        const int* __restrict__ srcp, const int* __restrict__ dstp, const int* __restrict__ sppos,
        float* __restrict__ mbuf, int E)
{
    __shared__ float T[HD][68];
    __shared__ int s_src[64], s_dst[64], s_sp[64];
    const int t = threadIdx.x;
    const int row0 = blockIdx.x * 64;
    if (t < 64) {
        const int e = row0 + t;
        s_src[t] = (e < E) ? srcp[e] : 0;
        s_dst[t] = (e < E) ? dstp[e] : 0;
        s_sp[t]  = (e < E) ? sppos[e] : 0;
    }
    {
        const int r = t & 63, q = t >> 6;
        const int e = row0 + r;
        const bool ok = e < E;
        const float* p = ea + (size_t)e * HD + q * 32;
        #pragma unroll
        for (int kk = 0; kk < 8; ++kk) {
            float4 v = ok ? *(const float4*)(p + kk * 4) : make_float4(0.f,0.f,0.f,0.f);
            const int k = q * 32 + kk * 4;
            T[k+0][r]=v.x; T[k+1][r]=v.y; T[k+2][r]=v.z; T[k+3][r]=v.w;
        }
    }
    __syncthreads();
    const int cg = t & 15, rg = t >> 4;
    const int c0 = cg * 8, r0 = rg * 4;
    float acc[4][8] = {};
    #pragma unroll 8
    for (int k = 0; k < HD; ++k) {
        const float4 a  = *(const float4*)&T[k][r0];
        const float4 w0 = *(const float4*)(We + (size_t)k * HD + c0);
        const float4 w1 = *(const float4*)(We + (size_t)k * HD + c0 + 4);
        const float av[4] = {a.x, a.y, a.z, a.w};
        const float wv[8] = {w0.x, w0.y, w0.z, w0.w, w1.x, w1.y, w1.z, w1.w};
        #pragma unroll
        for (int i = 0; i < 4; ++i)
            #pragma unroll
            for (int j = 0; j < 8; ++j)
                acc[i][j] += av[i] * wv[j];
    }
    #pragma unroll
    for (int i = 0; i < 4; ++i) {
        const int e = row0 + r0 + i;
        if (e >= E) continue;
        const int dn = s_dst[r0 + i], sn = s_src[r0 + i], sp = s_sp[r0 + i];
        const float* pd = xd + (size_t)dn * HD + c0;
        const float* ps = xs + (size_t)sn * HD + c0;
        const float4 d0 = *(const float4*)pd, d1 = *(const float4*)(pd + 4);
        const float4 s0 = *(const float4*)ps, s1 = *(const float4*)(ps + 4);
        float* pm = mbuf + (size_t)sp * HD + c0;
        float4 o0 = make_float4(acc[i][0]+d0.x+s0.x, acc[i][1]+d0.y+s0.y,
                                acc[i][2]+d0.z+s0.z, acc[i][3]+d0.w+s0.w);
        float4 o1 = make_float4(acc[i][4]+d1.x+s1.x, acc[i][5]+d1.y+s1.y,
                                acc[i][6]+d1.z+s1.z, acc[i][7]+d1.w+s1.w);
        *(float4*)(pm)     = o0;
        *(float4*)(pm + 4) = o1;
    }
}

// ---- CSR aggregation: one wave per node; agg[n] = [mean | mn | mx | std] (512 floats) ----
__global__ void __launch_bounds__(256) k_agg(const float* __restrict__ mbuf,
        const int* __restrict__ rs, float* __restrict__ agg)
{
    const int n = blockIdx.x * 4 + (threadIdx.x >> 6);
    if (n >= NN) return;
    const int lane = threadIdx.x & 63;
    const int c = lane * 2;
    const int s = rs[n], e = rs[n + 1];
    float s0=0.f, s1=0.f, q0=0.f, q1=0.f;
    float mn0=INFINITY, mn1=INFINITY, mx0=-INFINITY, mx1=-INFINITY;
    for (int i = s; i < e; ++i) {
        const float2 v = *(const float2*)(mbuf + (size_t)i * HD + c);
        s0 += v.x; s1 += v.y;
        q0 += v.x * v.x; q1 += v.y * v.y;
        mn0 = fminf(mn0, v.x); mn1 = fminf(mn1, v.y);
        mx0 = fmaxf(mx0, v.x); mx1 = fmaxf(mx1, v.y);
    }
    const int deg = e - s;
    const float inv = 1.f / (float)(deg > 1 ? deg : 1);
    const float m0 = s0 * inv, m1 = s1 * inv;
    const float sd0 = sqrtf(fmaxf(q0 * inv - m0 * m0, 0.f) + 1e-5f);
    const float sd1 = sqrtf(fmaxf(q1 * inv - m1 * m1, 0.f) + 1e-5f);
    const bool has = deg > 0;
    float* a = agg + (size_t)n * 512 + c;
    *(float2*)(a)       = make_float2(m0, m1);
    *(float2*)(a + 128) = has ? make_float2(mn0, mn1) : make_float2(0.f, 0.f);
    *(float2*)(a + 256) = has ? make_float2(mx0, mx1) : make_float2(0.f, 0.f);
    *(float2*)(a + 384) = make_float2(sd0, sd1);
}

// ---- post: out = x@B0 + sum_j aggj@B(1+j) + amp*sum_j aggj@B(5+j) + att*sum_j aggj@B(9+j) + pb ----
__global__ void __launch_bounds__(256) k_post(const float* __restrict__ x,
        const float* __restrict__ agg, const int* __restrict__ cnt, const float* __restrict__ stats,
        const float* __restrict__ PW, const float* __restrict__ pb,
        float* __restrict__ outb, int M)
{
    __shared__ float T[HD][68];
    __shared__ float s_cnt[64];
    const int t = threadIdx.x;
    const int row0 = blockIdx.x * 64;
    if (t < 64) {
        const int n = row0 + t;
        s_cnt[t] = (n < M) ? (float)cnt[n] : 0.f;
    }
    const int r = t & 63, q = t >> 6;
    const int nrow = row0 + r;
    const bool ok = nrow < M;
    const int cg = t & 15, rg = t >> 4;
    const int c0 = cg * 8, r0 = rg * 4;
    float accA[4][8] = {}, accB[4][8] = {}, accC[4][8] = {};

    // phase X: x @ PW[0:128]
    {
        const float* p = x + (size_t)nrow * HD + q * 32;
        #pragma unroll
        for (int kk = 0; kk < 8; ++kk) {
            float4 v = ok ? *(const float4*)(p + kk * 4) : make_float4(0.f,0.f,0.f,0.f);
            const int k = q * 32 + kk * 4;
            T[k+0][r]=v.x; T[k+1][r]=v.y; T[k+2][r]=v.z; T[k+3][r]=v.w;
        }
    }
    __syncthreads();
    #pragma unroll 4
    for (int k = 0; k < HD; ++k) {
        const float4 a  = *(const float4*)&T[k][r0];
        const float4 w0 = *(const float4*)(PW + (size_t)k * HD + c0);
        const float4 w1 = *(const float4*)(PW + (size_t)k * HD + c0 + 4);
        const float av[4] = {a.x, a.y, a.z, a.w};
        const float wv[8] = {w0.x, w0.y, w0.z, w0.w, w1.x, w1.y, w1.z, w1.w};
        #pragma unroll
        for (int i = 0; i < 4; ++i)
            #pragma unroll
            for (int j = 0; j < 8; ++j)
                accA[i][j] += av[i] * wv[j];
    }

    const size_t abase = (size_t)nrow * 512 + q * 32;

    for (int jb = 0; jb < 4; ++jb) {
        __syncthreads();
        #pragma unroll
        for (int kk = 0; kk < 8; ++kk) {
            const int k = q * 32 + kk * 4;
            float4 v = ok ? *(const float4*)(agg + abase + jb * 128 + kk * 4)
                          : make_float4(0.f,0.f,0.f,0.f);
            T[k+0][r]=v.x; T[k+1][r]=v.y; T[k+2][r]=v.z; T[k+3][r]=v.w;
        }
        __syncthreads();
        const float* W1 = PW + (size_t)(128  + jb * 128) * HD;
        const float* W2 = PW + (size_t)(640  + jb * 128) * HD;
        const float* W3 = PW + (size_t)(1152 + jb * 128) * HD;
        #pragma unroll 4
        for (int k = 0; k < HD; ++k) {
            const float4 a = *(const float4*)&T[k][r0];
            const float av[4] = {a.x, a.y, a.z, a.w};
            const float4 u0 = *(const float4*)(W1 + (size_t)k*HD + c0), u1 = *(const float4*)(W1 + (size_t)k*HD + c0 + 4);
            const float4 v0 = *(const float4*)(W2 + (size_t)k*HD + c0), v1 = *(const float4*)(W2 + (size_t)k*HD + c0 + 4);
            const float4 t0 = *(const float4*)(W3 + (size_t)k*HD + c0), t1 = *(const float4*)(W3 + (size_t)k*HD + c0 + 4);
            const float w1v[8] = {u0.x,u0.y,u0.z,u0.w,u1.x,u1.y,u1.z,u1.w};
            const float w2v[8] = {v0.x,v0.y,v0.z,v0.w,v1.x,v1.y,v1.z,v1.w};
            const float w3v[8] = {t0.x,t0.y,t0.z,t0.w,t1.x,t1.y,t1.z,t1.w};
            #pragma unroll
            for (int i = 0; i < 4; ++i)
                #pragma unroll
                for (int j = 0; j < 8; ++j) {
                    accA[i][j] += av[i] * w1v[j];
                    accB[i][j] += av[i] * w2v[j];
                    accC[i][j] += av[i] * w3v[j];
                }
        }
    }
    const float avg = stats[0] * (1.f / (float)NN);
    float bv[8];
    #pragma unroll
    for (int j = 0; j < 8; ++j) bv[j] = pb[c0 + j];
    #pragma unroll
    for (int i = 0; i < 4; ++i) {
        const int n = row0 + r0 + i;
        if (n >= M) continue;
        const float c  = s_cnt[r0 + i];
        const float lg = logf(fmaxf(c, 1.f) + 1.f);
        const float amp = lg / avg, att = avg / lg;
        float o[8];
        #pragma unroll
        for (int j = 0; j < 8; ++j)
            o[j] = accA[i][j] + amp * accB[i][j] + att * accC[i][j] + bv[j];
        *(float4*)(outb + (size_t)n * HD + c0)     = make_float4(o[0],o[1],o[2],o[3]);
        *(float4*)(outb + (size_t)n * HD + c0 + 4) = make_float4(o[4],o[5],o[6],o[7]);
    }
}

// ---- BN column sums ----
__global__ void __launch_bounds__(256) k_bnstats(const float* __restrict__ ob,
        float* __restrict__ bs, float* __restrict__ bq, int M)
{
    const int c = threadIdx.x & 127;
    const int gsub = threadIdx.x >> 7;
    float s = 0.f, qq = 0.f;
    for (int rr = blockIdx.x * 2 + gsub; rr < M; rr += gridDim.x * 2) {
        const float v = ob[(size_t)rr * HD + c];
        s += v; qq += v * v;
    }
    __shared__ float ls[2][HD], lq[2][HD];
    ls[gsub][c] = s; lq[gsub][c] = qq;
    __syncthreads();
    if (gsub == 0) {
        unsafeAtomicAdd(&bs[c], ls[0][c] + ls[1][c]);
        unsafeAtomicAdd(&bq[c], lq[0][c] + lq[1][c]);
    }
}

// ---- x = (x + relu(bn(out)))/2 ----
__global__ void __launch_bounds__(256) k_xupdate(float* x, const float* __restrict__ ob,
        const float* __restrict__ bs, const float* __restrict__ bq,
        const float* __restrict__ g, const float* __restrict__ bb)
{
    const int i = blockIdx.x * 256 + threadIdx.x;   // float4 index; grid sized exactly
    const int c0 = (i & 31) * 4;
    const float4 ov = ((const float4*)ob)[i];
    const float4 xv = ((const float4*)x)[i];
    const float o[4]  = {ov.x, ov.y, ov.z, ov.w};
    const float xo[4] = {xv.x, xv.y, xv.z, xv.w};
    float res[4];
    #pragma unroll
    for (int j = 0; j < 4; ++j) {
        const int c = c0 + j;
        const float mu  = bs[c] * (1.f / (float)NN);
        const float var = bq[c] * (1.f / (float)NN) - mu * mu;
        const float bn  = g[c] * (o[j] - mu) * rsqrtf(var + 1e-5f) + bb[c];
        res[j] = (xo[j] + fmaxf(bn, 0.f)) * 0.5f;
    }
    ((float4*)x)[i] = make_float4(res[0], res[1], res[2], res[3]);
}

// ---- edge update: hid = relu(ea@W1e + xs1[src] + xd1[dst]); ea += (hid@em2 + e2b)/2 ----
__global__ void __launch_bounds__(256) k_edge_upd(float* ea, const float* __restrict__ W1e,
        const float* __restrict__ e2W, const float* __restrict__ e2b,
        const float* __restrict__ xs1, const float* __restrict__ xd1,
        const int* __restrict__ srcp, const int* __restrict__ dstp, int E)
{
    __shared__ float T[HD][68];
    __shared__ int s_src[64], s_dst[64];
    const int t = threadIdx.x;
    const int row0 = blockIdx.x * 64;
    if (t < 64) {
        const int e = row0 + t;
        s_src[t] = (e < E) ? srcp[e] : 0;
        s_dst[t] = (e < E) ? dstp[e] : 0;
    }
    {
        const int r = t & 63, q = t >> 6;
        const int e = row0 + r;
        const bool ok = e < E;
        const float* p = ea + (size_t)e * HD + q * 32;
        #pragma unroll
        for (int kk = 0; kk < 8; ++kk) {
            float4 v = ok ? *(const float4*)(p + kk * 4) : make_float4(0.f,0.f,0.f,0.f);
            const int k = q * 32 + kk * 4;
            T[k+0][r]=v.x; T[k+1][r]=v.y; T[k+2][r]=v.z; T[k+3][r]=v.w;
        }
    }
    __syncthreads();
    const int cg = t & 15, rg = t >> 4;
    const int c0 = cg * 8, r0 = rg * 4;
    float acc[4][8] = {};
    #pragma unroll 8
    for (int k = 0; k < HD; ++k) {
        const float4 a  = *(const float4*)&T[k][r0];
        const float4 w0 = *(const float4*)(W1e + (size_t)k * HD + c0);
        const float4 w1 = *(const float4*)(W1e + (size_t)k * HD + c0 + 4);
        const float av[4] = {a.x, a.y, a.z, a.w};
        const float wv[8] = {w0.x, w0.y, w0.z, w0.w, w1.x, w1.y, w1.z, w1.w};
        #pragma unroll
        for (int i = 0; i < 4; ++i)
            #pragma unroll
            for (int j = 0; j < 8; ++j)
                acc[i][j] += av[i] * wv[j];
    }
    // save own ea tile, compute hid
    float eaold[4][8], hid[4][8];
    #pragma unroll
    for (int i = 0; i < 4; ++i) {
        #pragma unroll
        for (int j = 0; j < 8; ++j) eaold[i][j] = T[c0 + j][r0 + i];
        const int sn = s_src[r0 + i], dn = s_dst[r0 + i];
        const float* ps = xs1 + (size_t)sn * HD + c0;
        const float* pd = xd1 + (size_t)dn * HD + c0;
        const float4 s0 = *(const float4*)ps, s1 = *(const float4*)(ps + 4);
        const float4 d0 = *(const float4*)pd, d1 = *(const float4*)(pd + 4);
        const float sv[8] = {s0.x,s0.y,s0.z,s0.w,s1.x,s1.y,s1.z,s1.w};
        const float dv[8] = {d0.x,d0.y,d0.z,d0.w,d1.x,d1.y,d1.z,d1.w};
        #pragma unroll
        for (int j = 0; j < 8; ++j)
            hid[i][j] = fmaxf(acc[i][j] + sv[j] + dv[j], 0.f);
    }
    __syncthreads();            // all reads of T (gemm1 + eaold) complete
    #pragma unroll
    for (int i = 0; i < 4; ++i)
        #pragma unroll
        for (int j = 0; j < 8; ++j)
            T[c0 + j][r0 + i] = hid[i][j];
    __syncthreads();
    float acc2[4][8] = {};
    #pragma unroll 8
    for (int k = 0; k < HD; ++k) {
        const float4 a  = *(const float4*)&T[k][r0];
        const float4 w0 = *(const float4*)(e2W + (size_t)k * HD + c0);
        const float4 w1 = *(const float4*)(e2W + (size_t)k * HD + c0 + 4);
        const float av[4] = {a.x, a.y, a.z, a.w};
        const float wv[8] = {w0.x, w0.y, w0.z, w0.w, w1.x, w1.y, w1.z, w1.w};
        #pragma unroll
        for (int i = 0; i < 4; ++i)
            #pragma unroll
            for (int j = 0; j < 8; ++j)
                acc2[i][j] += av[i] * wv[j];
    }
    float bv[8];
    #pragma unroll
    for (int j = 0; j < 8; ++j) bv[j] = e2b[c0 + j];
    #pragma unroll
    for (int i = 0; i < 4; ++i) {
        const int e = row0 + r0 + i;
        if (e >= E) continue;
        float o[8];
        #pragma unroll
        for (int j = 0; j < 8; ++j)
            o[j] = eaold[i][j] + (acc2[i][j] + bv[j]) * 0.5f;
        *(float4*)(ea + (size_t)e * HD + c0)     = make_float4(o[0],o[1],o[2],o[3]);
        *(float4*)(ea + (size_t)e * HD + c0 + 4) = make_float4(o[4],o[5],o[6],o[7]);
    }
}

extern "C" void kernel_launch(void* const* d_in, const int* in_sizes, int n_in,
                              void* d_out, int out_size, void* d_ws, size_t ws_size,
                              hipStream_t stream)
{
    const float* x0    = (const float*)d_in[0];
    const float* eatr  = (const float*)d_in[1];
    const float* teatr = (const float*)d_in[2];
    const float* nodeW = (const float*)d_in[3];
    const float* nodeb = (const float*)d_in[4];
    const float* edgeW = (const float*)d_in[5];
    const float* edgeb = (const float*)d_in[6];
    const float* preW  = (const float*)d_in[7];
    const float* preb  = (const float*)d_in[8];
    const float* postW = (const float*)d_in[9];
    const float* postb = (const float*)d_in[10];
    const float* linW  = (const float*)d_in[11];
    const float* linb  = (const float*)d_in[12];
    const float* bng   = (const float*)d_in[13];
    const float* bnb   = (const float*)d_in[14];
    const float* em1W  = (const float*)d_in[15];
    const float* em1b  = (const float*)d_in[16];
    const float* em2W  = (const float*)d_in[17];
    const float* em2b  = (const float*)d_in[18];
    const int*   eidx  = (const int*)d_in[19];
    const int* srcp = eidx;
    const int* dstp = eidx + NE;

    float* out_x  = (float*)d_out;
    float* out_ea = out_x + (size_t)NN * HD;
    float* out_te = out_ea + (size_t)NE * HD;

    const size_t NH = (size_t)NN * HD;
    const size_t EH = (size_t)NE * HD;
    float* xd   = (float*)d_ws;
    float* xs   = xd + NH;
    float* agg  = xs + NH;          // [NN][512]: mean | mn | mx | std
    float* outb = agg + 4 * NH;
    float* mbuf = outb + NH;        // [NE][128] messages in CSR order
    float* stats = mbuf + EH;       // [0]=sum log; [128..255]=bn sum; [256..383]=bn sumsq
    int*   cnt      = (int*)(stats + 512);
    int*   row_start = cnt + NN;    // NN+1
    int*   cursor   = row_start + NN + 1;
    int*   tmpincl  = cursor + NN;
    int*   part     = tmpincl + NN;     // 256
    int*   poff     = part + 256;       // 256
    int*   sppos    = poff + 256;       // NE

    hipMemsetAsync(cnt, 0, NN * sizeof(int), stream);
    hipMemsetAsync(stats, 0, 512 * sizeof(float), stream);

    // prologue embeddings
    k_gemm_rm<EDIM><<<(NE + 63) / 64, 256, 0, stream>>>(eatr, edgeW, edgeb, out_ea, NE);
    k_gemm_rm<EDIM><<<(NTE + 63) / 64, 256, 0, stream>>>(teatr, edgeW, edgeb, out_te, NTE);
    k_gemm_rm<FIN><<<(NN + 63) / 64, 256, 0, stream>>>(x0, nodeW, nodeb, out_x, NN);

    // CSR build
    k_count<<<(NE + 255) / 256, 256, 0, stream>>>(dstp, cnt, NE);
    k_avglog<<<256, 256, 0, stream>>>(cnt, stats);
    k_scan_block<<<SCAN_B, 256, 0, stream>>>(cnt, tmpincl, part);
    k_scan_part<<<1, 256, 0, stream>>>(part, poff, SCAN_B);
    k_scan_add<<<SCAN_B, 256, 0, stream>>>(tmpincl, cnt, poff, row_start, cursor);
    k_scatter<<<(NE + 255) / 256, 256, 0, stream>>>(dstp, cursor, sppos);

    const int gn = (NN + 63) / 64;
    const int ge = (NE + 63) / 64;

    for (int l = 0; l < NL; ++l) {
        const float* Wd  = preW + (size_t)l * 384 * HD;
        const float* Ws_ = Wd + 128 * HD;
        const float* We  = Wd + 256 * HD;
        const float* pbl = preb + l * HD;
        const float* PW  = postW + (size_t)l * 1664 * HD;
        const float* pob = postb + l * HD;
        const float* lW  = linW + (size_t)l * HD * HD;
        const float* lb  = linb + l * HD;
        const float* g_  = bng + l * HD;
        const float* b_  = bnb + l * HD;
        const float* W1s = em1W + (size_t)l * 384 * HD;
        const float* W1d = W1s + 128 * HD;
        const float* W1e = W1s + 256 * HD;
        const float* e1b = em1b + l * HD;
        const float* e2W = em2W + (size_t)l * HD * HD;
        const float* e2b = em2b + l * HD;

        hipMemsetAsync(stats + 128, 0, 256 * sizeof(float), stream);

        k_gemm_rm<HD><<<gn, 256, 0, stream>>>(out_x, Wd, pbl, xd, NN);
        k_gemm_rm<HD><<<gn, 256, 0, stream>>>(out_x, Ws_, nullptr, xs, NN);
        k_msg<<<ge, 256, 0, stream>>>(out_ea, We, xd, xs, srcp, dstp, sppos, mbuf, NE);
        k_agg<<<(NN + 3) / 4, 256, 0, stream>>>(mbuf, row_start, agg);
        k_post<<<gn, 256, 0, stream>>>(out_x, agg, cnt, stats, PW, pob, outb, NN);
        k_gemm_rm<HD><<<gn, 256, 0, stream>>>(outb, lW, lb, outb, NN);   // in-place lin
        k_bnstats<<<256, 256, 0, stream>>>(outb, stats + 128, stats + 256, NN);
        k_xupdate<<<NN * 32 / 256, 256, 0, stream>>>(out_x, outb, stats + 128, stats + 256, g_, b_);
        k_gemm_rm<HD><<<gn, 256, 0, stream>>>(out_x, W1s, nullptr, xs, NN);   // xs1
        k_gemm_rm<HD><<<gn, 256, 0, stream>>>(out_x, W1d, e1b, xd, NN);       // xd1 (+em1_b)
        k_edge_upd<<<ge, 256, 0, stream>>>(out_ea, W1e, e2W, e2b, xs, xd, srcp, dstp, NE);
    }
}

// Round 3
// 2512.669 us; speedup vs baseline: 5.1308x; 1.9248x over previous
//
#include <hip/hip_runtime.h>
#include <math.h>

#define NN  50000
#define NE  400000
#define NTE 50000
#define FIN 64
#define EDIM 32
#define HD  128
#define NL  2
#define SCAN_B ((NN + 255) / 256)

typedef __attribute__((ext_vector_type(8))) short bf16x8;
typedef __attribute__((ext_vector_type(4))) float f32x4;

static __device__ __forceinline__ unsigned short f2bf(float f) {
    unsigned u = __float_as_uint(f);
    unsigned r = (u + 0x7fffu + ((u >> 16) & 1u)) >> 16;
    return (unsigned short)r;
}

static __device__ __forceinline__ bf16x8 load_a8(const float* p, bool ok) {
    bf16x8 a = {};
    if (ok) {
        const float4 v0 = *(const float4*)(p);
        const float4 v1 = *(const float4*)(p + 4);
        a[0] = (short)f2bf(v0.x); a[1] = (short)f2bf(v0.y);
        a[2] = (short)f2bf(v0.z); a[3] = (short)f2bf(v0.w);
        a[4] = (short)f2bf(v1.x); a[5] = (short)f2bf(v1.y);
        a[6] = (short)f2bf(v1.z); a[7] = (short)f2bf(v1.w);
    }
    return a;
}

// ---- pack fp32 W[K][128] into bf16 MFMA B-frag order: [(kb*8+nt)*64+lane][8] k-contig ----
__global__ void __launch_bounds__(256) k_packW(const float* __restrict__ W,
        unsigned short* __restrict__ out, int K)
{
    const int tid = blockIdx.x * 256 + threadIdx.x;
    const int total = (K / 32) * 512;
    if (tid >= total) return;
    const int lane = tid & 63, nt = (tid >> 6) & 7, kb = tid >> 9;
    const int k0 = kb * 32 + (lane >> 4) * 8;
    const int col = nt * 16 + (lane & 15);
    bf16x8 v;
    #pragma unroll
    for (int j = 0; j < 8; ++j)
        v[j] = (short)f2bf(W[(size_t)(k0 + j) * HD + col]);
    *(bf16x8*)(out + (size_t)tid * 8) = v;
}

// ---- MFMA GEMM: C[M x 128] = A[M x 128] @ Wpk (+bias). A fp32. In-place safe. ----
__global__ void __launch_bounds__(256) k_gemm_mfma(const float* A,
        const unsigned short* __restrict__ Wpk, const float* __restrict__ bias,
        float* C, int M)
{
    const int t = threadIdx.x, w = t >> 6, l = t & 63;
    const int row0b = blockIdx.x * 64;
    const int row0 = row0b + w * 16;
    const int ar = row0 + (l & 15);
    const bool aok = ar < M;
    const int kq = (l >> 4) * 8;
    f32x4 acc[8] = {};
    #pragma unroll
    for (int kb = 0; kb < 4; ++kb) {
        const bf16x8 a = load_a8(A + (size_t)ar * HD + kb * 32 + kq, aok);
        #pragma unroll
        for (int nt = 0; nt < 8; ++nt) {
            const bf16x8 b = *(const bf16x8*)(Wpk + (((size_t)(kb * 8 + nt) * 64 + l) << 3));
            acc[nt] = __builtin_amdgcn_mfma_f32_16x16x32_bf16(a, b, acc[nt], 0, 0, 0);
        }
    }
    #pragma unroll
    for (int nt = 0; nt < 8; ++nt) {
        const int col = nt * 16 + (l & 15);
        const float bv = bias ? bias[col] : 0.f;
        #pragma unroll
        for (int r = 0; r < 4; ++r) {
            const int orow = row0 + (l >> 4) * 4 + r;
            if (orow < M) C[(size_t)orow * HD + col] = acc[nt][r] + bv;
        }
    }
}

// ---- MFMA post: out = [x|agg] @ PW with amp/att row scaling ----
__global__ void __launch_bounds__(256) k_post_mfma(const float* __restrict__ x,
        const float* __restrict__ agg, const int* __restrict__ cnt,
        const float* __restrict__ stats, const unsigned short* __restrict__ PWpk,
        const float* __restrict__ pb, float* __restrict__ outb, int M)
{
    __shared__ float s_amp[64], s_att[64];
    const int t = threadIdx.x;
    const int row0b = blockIdx.x * 64;
    if (t < 64) {
        const int n = row0b + t;
        const float cf = (n < M) ? (float)cnt[n] : 1.f;
        const float avg = stats[0] * (1.f / (float)NN);
        const float lg = logf(fmaxf(cf, 1.f) + 1.f);
        s_amp[t] = lg / avg;
        s_att[t] = avg / lg;
    }
    __syncthreads();
    const int w = t >> 6, l = t & 63;
    const int row0 = row0b + w * 16;
    const int ar = row0 + (l & 15);
    const bool aok = ar < M;
    const int kq = (l >> 4) * 8;
    f32x4 aA[8] = {}, aB[8] = {}, aC[8] = {};

    // x region: global kb 0..3
    #pragma unroll
    for (int kb = 0; kb < 4; ++kb) {
        const bf16x8 a = load_a8(x + (size_t)ar * HD + kb * 32 + kq, aok);
        #pragma unroll
        for (int nt = 0; nt < 8; ++nt) {
            const bf16x8 b = *(const bf16x8*)(PWpk + (((size_t)(kb * 8 + nt) * 64 + l) << 3));
            aA[nt] = __builtin_amdgcn_mfma_f32_16x16x32_bf16(a, b, aA[nt], 0, 0, 0);
        }
    }
    // agg region: 4 agg sub-blocks (mean|mn|mx|std), three W panels each
    for (int jb = 0; jb < 4; ++jb) {
        #pragma unroll
        for (int k2 = 0; k2 < 4; ++k2) {
            const bf16x8 a = load_a8(agg + (size_t)ar * 512 + jb * 128 + k2 * 32 + kq, aok);
            const int kb1 = 4  + jb * 4 + k2;
            const int kb2 = 20 + jb * 4 + k2;
            const int kb3 = 36 + jb * 4 + k2;
            #pragma unroll
            for (int nt = 0; nt < 8; ++nt) {
                const bf16x8 b1 = *(const bf16x8*)(PWpk + (((size_t)(kb1 * 8 + nt) * 64 + l) << 3));
                const bf16x8 b2 = *(const bf16x8*)(PWpk + (((size_t)(kb2 * 8 + nt) * 64 + l) << 3));
                const bf16x8 b3 = *(const bf16x8*)(PWpk + (((size_t)(kb3 * 8 + nt) * 64 + l) << 3));
                aA[nt] = __builtin_amdgcn_mfma_f32_16x16x32_bf16(a, b1, aA[nt], 0, 0, 0);
                aB[nt] = __builtin_amdgcn_mfma_f32_16x16x32_bf16(a, b2, aB[nt], 0, 0, 0);
                aC[nt] = __builtin_amdgcn_mfma_f32_16x16x32_bf16(a, b3, aC[nt], 0, 0, 0);
            }
        }
    }
    #pragma unroll
    for (int nt = 0; nt < 8; ++nt) {
        const int col = nt * 16 + (l & 15);
        const float bv = pb[col];
        #pragma unroll
        for (int r = 0; r < 4; ++r) {
            const int lr = w * 16 + (l >> 4) * 4 + r;
            const int orow = row0b + lr;
            if (orow < M)
                outb[(size_t)orow * HD + col] =
                    aA[nt][r] + s_amp[lr] * aB[nt][r] + s_att[lr] * aC[nt][r] + bv;
        }
    }
}

// ---- generic fp32 GEMM (kept for K=32/64 embeddings) ----
template<int K>
__global__ void __launch_bounds__(256) k_gemm_rm(const float* A, const float* __restrict__ W,
                                                 const float* __restrict__ bias, float* C, int M)
{
    __shared__ float T[K][68];
    const int t = threadIdx.x;
    const int row0 = blockIdx.x * 64;
    {
        const int r = t & 63, q = t >> 6;
        const int grow = row0 + r;
        const bool ok = grow < M;
        const float* p = A + (size_t)grow * K + q * (K / 4);
        #pragma unroll
        for (int kk = 0; kk < K / 16; ++kk) {
            float4 v = ok ? *(const float4*)(p + kk * 4) : make_float4(0.f, 0.f, 0.f, 0.f);
            const int k = q * (K / 4) + kk * 4;
            T[k + 0][r] = v.x; T[k + 1][r] = v.y; T[k + 2][r] = v.z; T[k + 3][r] = v.w;
        }
    }
    __syncthreads();
    const int cg = t & 15, rg = t >> 4;
    const int c0 = cg * 8, r0 = rg * 4;
    float acc[4][8] = {};
    #pragma unroll 8
    for (int k = 0; k < K; ++k) {
        const float4 a  = *(const float4*)&T[k][r0];
        const float4 w0 = *(const float4*)(W + (size_t)k * HD + c0);
        const float4 w1 = *(const float4*)(W + (size_t)k * HD + c0 + 4);
        const float av[4] = {a.x, a.y, a.z, a.w};
        const float wv[8] = {w0.x, w0.y, w0.z, w0.w, w1.x, w1.y, w1.z, w1.w};
        #pragma unroll
        for (int i = 0; i < 4; ++i)
            #pragma unroll
            for (int j = 0; j < 8; ++j)
                acc[i][j] += av[i] * wv[j];
    }
    float bv[8];
    #pragma unroll
    for (int j = 0; j < 8; ++j) bv[j] = bias ? bias[c0 + j] : 0.f;
    #pragma unroll
    for (int i = 0; i < 4; ++i) {
        const int grow = row0 + r0 + i;
        if (grow < M) {
            float4 o0 = make_float4(acc[i][0]+bv[0], acc[i][1]+bv[1], acc[i][2]+bv[2], acc[i][3]+bv[3]);
            float4 o1 = make_float4(acc[i][4]+bv[4], acc[i][5]+bv[5], acc[i][6]+bv[6], acc[i][7]+bv[7]);
            *(float4*)(C + (size_t)grow * HD + c0)     = o0;
            *(float4*)(C + (size_t)grow * HD + c0 + 4) = o1;
        }
    }
}

// ---- degree count ----
__global__ void __launch_bounds__(256) k_count(const int* __restrict__ d, int* __restrict__ cnt, int E)
{
    const int e = blockIdx.x * 256 + threadIdx.x;
    if (e < E) atomicAdd(&cnt[d[e]], 1);
}

// ---- mean(log(cnt+1)) numerator ----
__global__ void __launch_bounds__(256) k_avglog(const int* __restrict__ cnt, float* __restrict__ stats)
{
    float s = 0.f;
    for (int n = blockIdx.x * 256 + threadIdx.x; n < NN; n += gridDim.x * 256)
        s += logf((float)cnt[n] + 1.f);
    #pragma unroll
    for (int off = 32; off > 0; off >>= 1) s += __shfl_down(s, off);
    __shared__ float ls[4];
    if ((threadIdx.x & 63) == 0) ls[threadIdx.x >> 6] = s;
    __syncthreads();
    if (threadIdx.x == 0) unsafeAtomicAdd(stats, ls[0] + ls[1] + ls[2] + ls[3]);
}

// ---- CSR build: block inclusive scan ----
__global__ void __launch_bounds__(256) k_scan_block(const int* __restrict__ cnt,
        int* __restrict__ incl, int* __restrict__ part)
{
    __shared__ int s[256];
    const int t = threadIdx.x;
    const int i = blockIdx.x * 256 + t;
    const int v = (i < NN) ? cnt[i] : 0;
    s[t] = v;
    __syncthreads();
    #pragma unroll
    for (int off = 1; off < 256; off <<= 1) {
        const int x = (t >= off) ? s[t - off] : 0;
        __syncthreads();
        s[t] += x;
        __syncthreads();
    }
    if (i < NN) incl[i] = s[t];
    if (t == 255) part[blockIdx.x] = s[255];
}

__global__ void __launch_bounds__(256) k_scan_part(const int* __restrict__ part,
        int* __restrict__ poff, int np)
{
    __shared__ int s[256];
    const int t = threadIdx.x;
    const int v = (t < np) ? part[t] : 0;
    s[t] = v;
    __syncthreads();
    #pragma unroll
    for (int off = 1; off < 256; off <<= 1) {
        const int x = (t >= off) ? s[t - off] : 0;
        __syncthreads();
        s[t] += x;
        __syncthreads();
    }
    poff[t] = s[t] - v;  // exclusive
}

__global__ void __launch_bounds__(256) k_scan_add(const int* __restrict__ incl,
        const int* __restrict__ cnt, const int* __restrict__ poff,
        int* __restrict__ row_start, int* __restrict__ cursor)
{
    const int i = blockIdx.x * 256 + threadIdx.x;
    if (i < NN) {
        const int excl = incl[i] - cnt[i] + poff[blockIdx.x];
        row_start[i] = excl;
        cursor[i] = excl;
    }
    if (i == 0) row_start[NN] = NE;
}

__global__ void __launch_bounds__(256) k_scatter(const int* __restrict__ dstp,
        int* cursor, int* __restrict__ sppos)
{
    const int e = blockIdx.x * 256 + threadIdx.x;
    if (e < NE) sppos[e] = atomicAdd(&cursor[dstp[e]], 1);
}

// ---- fused: m = ea@We + xd[dst] + xs[src] (bias folded into xd); row-scatter into mbuf[sppos] ----
__global__ void __launch_bounds__(256) k_msg(const float* __restrict__ ea,
        const float* __restrict__ We, const float* __restrict__ xd, const float* __restrict__ xs,
        const int* __restrict__ srcp, const int* __restrict__ dstp, const int* __restrict__ sppos,
        float* __restrict__ mbuf, int E)
{
    __shared__ float T[HD][68];
    __shared__ int s_src[64], s_dst[64], s_sp[64];
    const int t = threadIdx.x;
    const int row0 = blockIdx.x * 64;
    if (t < 64) {
        const int e = row0 + t;
        s_src[t] = (e < E) ? srcp[e] : 0;
        s_dst[t] = (e < E) ? dstp[e] : 0;
        s_sp[t]  = (e < E) ? sppos[e] : 0;
    }
    {
        const int r = t & 63, q = t >> 6;
        const int e = row0 + r;
        const bool ok = e < E;
        const float* p = ea + (size_t)e * HD + q * 32;
        #pragma unroll
        for (int kk = 0; kk < 8; ++kk) {
            float4 v = ok ? *(const float4*)(p + kk * 4) : make_float4(0.f,0.f,0.f,0.f);
            const int k = q * 32 + kk * 4;
            T[k+0][r]=v.x; T[k+1][r]=v.y; T[k+2][r]=v.z; T[k+3][r]=v.w;
        }
    }
    __syncthreads();
    const int cg = t & 15, rg = t >> 4;
    const int c0 = cg * 8, r0 = rg * 4;
    float acc[4][8] = {};
    #pragma unroll 8
    for (int k = 0; k < HD; ++k) {
        const float4 a  = *(const float4*)&T[k][r0];
        const float4 w0 = *(const float4*)(We + (size_t)k * HD + c0);
        const float4 w1 = *(const float4*)(We + (size_t)k * HD + c0 + 4);
        const float av[4] = {a.x, a.y, a.z, a.w};
        const float wv[8] = {w0.x, w0.y, w0.z, w0.w, w1.x, w1.y, w1.z, w1.w};
        #pragma unroll
        for (int i = 0; i < 4; ++i)
            #pragma unroll
            for (int j = 0; j < 8; ++j)
                acc[i][j] += av[i] * wv[j];
    }
    #pragma unroll
    for (int i = 0; i < 4; ++i) {
        const int e = row0 + r0 + i;
        if (e >= E) continue;
        const int dn = s_dst[r0 + i], sn = s_src[r0 + i], sp = s_sp[r0 + i];
        const float* pd = xd + (size_t)dn * HD + c0;
        const float* ps = xs + (size_t)sn * HD + c0;
        const float4 d0 = *(const float4*)pd, d1 = *(const float4*)(pd + 4);
        const float4 s0 = *(const float4*)ps, s1 = *(const float4*)(ps + 4);
        float* pm = mbuf + (size_t)sp * HD + c0;
        float4 o0 = make_float4(acc[i][0]+d0.x+s0.x, acc[i][1]+d0.y+s0.y,
                                acc[i][2]+d0.z+s0.z, acc[i][3]+d0.w+s0.w);
        float4 o1 = make_float4(acc[i][4]+d1.x+s1.x, acc[i][5]+d1.y+s1.y,
                                acc[i][6]+d1.z+s1.z, acc[i][7]+d1.w+s1.w);
        *(float4*)(pm)     = o0;
        *(float4*)(pm + 4) = o1;
    }
}

// ---- CSR aggregation: one wave per node; agg[n] = [mean | mn | mx | std] (512 floats) ----
__global__ void __launch_bounds__(256) k_agg(const float* __restrict__ mbuf,
        const int* __restrict__ rs, float* __restrict__ agg)
{
    const int n = blockIdx.x * 4 + (threadIdx.x >> 6);
    if (n >= NN) return;
    const int lane = threadIdx.x & 63;
    const int c = lane * 2;
    const int s = rs[n], e = rs[n + 1];
    float s0=0.f, s1=0.f, q0=0.f, q1=0.f;
    float mn0=INFINITY, mn1=INFINITY, mx0=-INFINITY, mx1=-INFINITY;
    for (int i = s; i < e; ++i) {
        const float2 v = *(const float2*)(mbuf + (size_t)i * HD + c);
        s0 += v.x; s1 += v.y;
        q0 += v.x * v.x; q1 += v.y * v.y;
        mn0 = fminf(mn0, v.x); mn1 = fminf(mn1, v.y);
        mx0 = fmaxf(mx0, v.x); mx1 = fmaxf(mx1, v.y);
    }
    const int deg = e - s;
    const float inv = 1.f / (float)(deg > 1 ? deg : 1);
    const float m0 = s0 * inv, m1 = s1 * inv;
    const float sd0 = sqrtf(fmaxf(q0 * inv - m0 * m0, 0.f) + 1e-5f);
    const float sd1 = sqrtf(fmaxf(q1 * inv - m1 * m1, 0.f) + 1e-5f);
    const bool has = deg > 0;
    float* a = agg + (size_t)n * 512 + c;
    *(float2*)(a)       = make_float2(m0, m1);
    *(float2*)(a + 128) = has ? make_float2(mn0, mn1) : make_float2(0.f, 0.f);
    *(float2*)(a + 256) = has ? make_float2(mx0, mx1) : make_float2(0.f, 0.f);
    *(float2*)(a + 384) = make_float2(sd0, sd1);
}

// ---- BN column sums ----
__global__ void __launch_bounds__(256) k_bnstats(const float* __restrict__ ob,
        float* __restrict__ bs, float* __restrict__ bq, int M)
{
    const int c = threadIdx.x & 127;
    const int gsub = threadIdx.x >> 7;
    float s = 0.f, qq = 0.f;
    for (int rr = blockIdx.x * 2 + gsub; rr < M; rr += gridDim.x * 2) {
        const float v = ob[(size_t)rr * HD + c];
        s += v; qq += v * v;
    }
    __shared__ float ls[2][HD], lq[2][HD];
    ls[gsub][c] = s; lq[gsub][c] = qq;
    __syncthreads();
    if (gsub == 0) {
        unsafeAtomicAdd(&bs[c], ls[0][c] + ls[1][c]);
        unsafeAtomicAdd(&bq[c], lq[0][c] + lq[1][c]);
    }
}

// ---- x = (x + relu(bn(out)))/2 ----
__global__ void __launch_bounds__(256) k_xupdate(float* x, const float* __restrict__ ob,
        const float* __restrict__ bs, const float* __restrict__ bq,
        const float* __restrict__ g, const float* __restrict__ bb)
{
    const int i = blockIdx.x * 256 + threadIdx.x;   // float4 index; grid sized exactly
    const int c0 = (i & 31) * 4;
    const float4 ov = ((const float4*)ob)[i];
    const float4 xv = ((const float4*)x)[i];
    const float o[4]  = {ov.x, ov.y, ov.z, ov.w};
    const float xo[4] = {xv.x, xv.y, xv.z, xv.w};
    float res[4];
    #pragma unroll
    for (int j = 0; j < 4; ++j) {
        const int c = c0 + j;
        const float mu  = bs[c] * (1.f / (float)NN);
        const float var = bq[c] * (1.f / (float)NN) - mu * mu;
        const float bn  = g[c] * (o[j] - mu) * rsqrtf(var + 1e-5f) + bb[c];
        res[j] = (xo[j] + fmaxf(bn, 0.f)) * 0.5f;
    }
    ((float4*)x)[i] = make_float4(res[0], res[1], res[2], res[3]);
}

// ---- edge update: hid = relu(ea@W1e + xs1[src] + xd1[dst]); ea += (hid@em2 + e2b)/2 ----
__global__ void __launch_bounds__(256) k_edge_upd(float* ea, const float* __restrict__ W1e,
        const float* __restrict__ e2W, const float* __restrict__ e2b,
        const float* __restrict__ xs1, const float* __restrict__ xd1,
        const int* __restrict__ srcp, const int* __restrict__ dstp, int E)
{
    __shared__ float T[HD][68];
    __shared__ int s_src[64], s_dst[64];
    const int t = threadIdx.x;
    const int row0 = blockIdx.x * 64;
    if (t < 64) {
        const int e = row0 + t;
        s_src[t] = (e < E) ? srcp[e] : 0;
        s_dst[t] = (e < E) ? dstp[e] : 0;
    }
    {
        const int r = t & 63, q = t >> 6;
        const int e = row0 + r;
        const bool ok = e < E;
        const float* p = ea + (size_t)e * HD + q * 32;
        #pragma unroll
        for (int kk = 0; kk < 8; ++kk) {
            float4 v = ok ? *(const float4*)(p + kk * 4) : make_float4(0.f,0.f,0.f,0.f);
            const int k = q * 32 + kk * 4;
            T[k+0][r]=v.x; T[k+1][r]=v.y; T[k+2][r]=v.z; T[k+3][r]=v.w;
        }
    }
    __syncthreads();
    const int cg = t & 15, rg = t >> 4;
    const int c0 = cg * 8, r0 = rg * 4;
    float acc[4][8] = {};
    #pragma unroll 8
    for (int k = 0; k < HD; ++k) {
        const float4 a  = *(const float4*)&T[k][r0];
        const float4 w0 = *(const float4*)(W1e + (size_t)k * HD + c0);
        const float4 w1 = *(const float4*)(W1e + (size_t)k * HD + c0 + 4);
        const float av[4] = {a.x, a.y, a.z, a.w};
        const float wv[8] = {w0.x, w0.y, w0.z, w0.w, w1.x, w1.y, w1.z, w1.w};
        #pragma unroll
        for (int i = 0; i < 4; ++i)
            #pragma unroll
            for (int j = 0; j < 8; ++j)
                acc[i][j] += av[i] * wv[j];
    }
    float eaold[4][8], hid[4][8];
    #pragma unroll
    for (int i = 0; i < 4; ++i) {
        #pragma unroll
        for (int j = 0; j < 8; ++j) eaold[i][j] = T[c0 + j][r0 + i];
        const int sn = s_src[r0 + i], dn = s_dst[r0 + i];
        const float* ps = xs1 + (size_t)sn * HD + c0;
        const float* pd = xd1 + (size_t)dn * HD + c0;
        const float4 s0 = *(const float4*)ps, s1 = *(const float4*)(ps + 4);
        const float4 d0 = *(const float4*)pd, d1 = *(const float4*)(pd + 4);
        const float sv[8] = {s0.x,s0.y,s0.z,s0.w,s1.x,s1.y,s1.z,s1.w};
        const float dv[8] = {d0.x,d0.y,d0.z,d0.w,d1.x,d1.y,d1.z,d1.w};
        #pragma unroll
        for (int j = 0; j < 8; ++j)
            hid[i][j] = fmaxf(acc[i][j] + sv[j] + dv[j], 0.f);
    }
    __syncthreads();
    #pragma unroll
    for (int i = 0; i < 4; ++i)
        #pragma unroll
        for (int j = 0; j < 8; ++j)
            T[c0 + j][r0 + i] = hid[i][j];
    __syncthreads();
    float acc2[4][8] = {};
    #pragma unroll 8
    for (int k = 0; k < HD; ++k) {
        const float4 a  = *(const float4*)&T[k][r0];
        const float4 w0 = *(const float4*)(e2W + (size_t)k * HD + c0);
        const float4 w1 = *(const float4*)(e2W + (size_t)k * HD + c0 + 4);
        const float av[4] = {a.x, a.y, a.z, a.w};
        const float wv[8] = {w0.x, w0.y, w0.z, w0.w, w1.x, w1.y, w1.z, w1.w};
        #pragma unroll
        for (int i = 0; i < 4; ++i)
            #pragma unroll
            for (int j = 0; j < 8; ++j)
                acc2[i][j] += av[i] * wv[j];
    }
    float bv[8];
    #pragma unroll
    for (int j = 0; j < 8; ++j) bv[j] = e2b[c0 + j];
    #pragma unroll
    for (int i = 0; i < 4; ++i) {
        const int e = row0 + r0 + i;
        if (e >= E) continue;
        float o[8];
        #pragma unroll
        for (int j = 0; j < 8; ++j)
            o[j] = eaold[i][j] + (acc2[i][j] + bv[j]) * 0.5f;
        *(float4*)(ea + (size_t)e * HD + c0)     = make_float4(o[0],o[1],o[2],o[3]);
        *(float4*)(ea + (size_t)e * HD + c0 + 4) = make_float4(o[4],o[5],o[6],o[7]);
    }
}

extern "C" void kernel_launch(void* const* d_in, const int* in_sizes, int n_in,
                              void* d_out, int out_size, void* d_ws, size_t ws_size,
                              hipStream_t stream)
{
    const float* x0    = (const float*)d_in[0];
    const float* eatr  = (const float*)d_in[1];
    const float* teatr = (const float*)d_in[2];
    const float* nodeW = (const float*)d_in[3];
    const float* nodeb = (const float*)d_in[4];
    const float* edgeW = (const float*)d_in[5];
    const float* edgeb = (const float*)d_in[6];
    const float* preW  = (const float*)d_in[7];
    const float* preb  = (const float*)d_in[8];
    const float* postW = (const float*)d_in[9];
    const float* postb = (const float*)d_in[10];
    const float* linW  = (const float*)d_in[11];
    const float* linb  = (const float*)d_in[12];
    const float* bng   = (const float*)d_in[13];
    const float* bnb   = (const float*)d_in[14];
    const float* em1W  = (const float*)d_in[15];
    const float* em1b  = (const float*)d_in[16];
    const float* em2W  = (const float*)d_in[17];
    const float* em2b  = (const float*)d_in[18];
    const int*   eidx  = (const int*)d_in[19];
    const int* srcp = eidx;
    const int* dstp = eidx + NE;

    float* out_x  = (float*)d_out;
    float* out_ea = out_x + (size_t)NN * HD;
    float* out_te = out_ea + (size_t)NE * HD;

    const size_t NH = (size_t)NN * HD;
    const size_t EH = (size_t)NE * HD;
    float* xd   = (float*)d_ws;
    float* xs   = xd + NH;
    float* agg  = xs + NH;          // [NN][512]: mean | mn | mx | std
    float* outb = agg + 4 * NH;
    float* mbuf = outb + NH;        // [NE][128] messages in CSR order
    float* stats = mbuf + EH;       // [0]=sum log; [128..255]=bn sum; [256..383]=bn sumsq
    int*   cnt      = (int*)(stats + 512);
    int*   row_start = cnt + NN;    // NN+1
    int*   cursor   = row_start + NN + 1;
    int*   tmpincl  = cursor + NN;
    int*   part     = tmpincl + NN;     // 256
    int*   poff     = part + 256;       // 256
    int*   sppos    = poff + 256;       // NE
    // packed bf16 weights (align up to 16 B)
    unsigned short* pkbase = (unsigned short*)(((uintptr_t)(sppos + NE) + 15) & ~(uintptr_t)15);
    const size_t PK_PW = (size_t)52 * 512 * 8;   // 1664/32 kbs
    const size_t PK_SQ = (size_t)4  * 512 * 8;   // 128/32 kbs
    unsigned short* pkPW[NL], *pkWd[NL], *pkWs[NL], *pkLin[NL], *pkW1s[NL], *pkW1d[NL];
    {
        unsigned short* p = pkbase;
        for (int l = 0; l < NL; ++l) { pkPW[l] = p; p += PK_PW; }
        for (int l = 0; l < NL; ++l) {
            pkWd[l]  = p; p += PK_SQ;
            pkWs[l]  = p; p += PK_SQ;
            pkLin[l] = p; p += PK_SQ;
            pkW1s[l] = p; p += PK_SQ;
            pkW1d[l] = p; p += PK_SQ;
        }
    }

    hipMemsetAsync(cnt, 0, NN * sizeof(int), stream);
    hipMemsetAsync(stats, 0, 512 * sizeof(float), stream);

    // pack weights (grid = K*16 threads)
    for (int l = 0; l < NL; ++l) {
        k_packW<<<104, 256, 0, stream>>>(postW + (size_t)l * 1664 * HD, pkPW[l], 1664);
        k_packW<<<8, 256, 0, stream>>>(preW + (size_t)l * 384 * HD,            pkWd[l],  128);
        k_packW<<<8, 256, 0, stream>>>(preW + (size_t)l * 384 * HD + 128 * HD, pkWs[l],  128);
        k_packW<<<8, 256, 0, stream>>>(linW + (size_t)l * HD * HD,             pkLin[l], 128);
        k_packW<<<8, 256, 0, stream>>>(em1W + (size_t)l * 384 * HD,            pkW1s[l], 128);
        k_packW<<<8, 256, 0, stream>>>(em1W + (size_t)l * 384 * HD + 128 * HD, pkW1d[l], 128);
    }

    // prologue embeddings
    k_gemm_rm<EDIM><<<(NE + 63) / 64, 256, 0, stream>>>(eatr, edgeW, edgeb, out_ea, NE);
    k_gemm_rm<EDIM><<<(NTE + 63) / 64, 256, 0, stream>>>(teatr, edgeW, edgeb, out_te, NTE);
    k_gemm_rm<FIN><<<(NN + 63) / 64, 256, 0, stream>>>(x0, nodeW, nodeb, out_x, NN);

    // CSR build
    k_count<<<(NE + 255) / 256, 256, 0, stream>>>(dstp, cnt, NE);
    k_avglog<<<256, 256, 0, stream>>>(cnt, stats);
    k_scan_block<<<SCAN_B, 256, 0, stream>>>(cnt, tmpincl, part);
    k_scan_part<<<1, 256, 0, stream>>>(part, poff, SCAN_B);
    k_scan_add<<<SCAN_B, 256, 0, stream>>>(tmpincl, cnt, poff, row_start, cursor);
    k_scatter<<<(NE + 255) / 256, 256, 0, stream>>>(dstp, cursor, sppos);

    const int gn = (NN + 63) / 64;
    const int ge = (NE + 63) / 64;

    for (int l = 0; l < NL; ++l) {
        const float* We  = preW + (size_t)l * 384 * HD + 256 * HD;
        const float* pbl = preb + l * HD;
        const float* pob = postb + l * HD;
        const float* lb  = linb + l * HD;
        const float* g_  = bng + l * HD;
        const float* b_  = bnb + l * HD;
        const float* W1e = em1W + (size_t)l * 384 * HD + 256 * HD;
        const float* e1b = em1b + l * HD;
        const float* e2W = em2W + (size_t)l * HD * HD;
        const float* e2b = em2b + l * HD;

        hipMemsetAsync(stats + 128, 0, 256 * sizeof(float), stream);

        k_gemm_mfma<<<gn, 256, 0, stream>>>(out_x, pkWd[l], pbl, xd, NN);
        k_gemm_mfma<<<gn, 256, 0, stream>>>(out_x, pkWs[l], nullptr, xs, NN);
        k_msg<<<ge, 256, 0, stream>>>(out_ea, We, xd, xs, srcp, dstp, sppos, mbuf, NE);
        k_agg<<<(NN + 3) / 4, 256, 0, stream>>>(mbuf, row_start, agg);
        k_post_mfma<<<gn, 256, 0, stream>>>(out_x, agg, cnt, stats, pkPW[l], pob, outb, NN);
        k_gemm_mfma<<<gn, 256, 0, stream>>>(outb, pkLin[l], lb, outb, NN);   // in-place lin
        k_bnstats<<<256, 256, 0, stream>>>(outb, stats + 128, stats + 256, NN);
        k_xupdate<<<NN * 32 / 256, 256, 0, stream>>>(out_x, outb, stats + 128, stats + 256, g_, b_);
        k_gemm_mfma<<<gn, 256, 0, stream>>>(out_x, pkW1s[l], nullptr, xs, NN);   // xs1
        k_gemm_mfma<<<gn, 256, 0, stream>>>(out_x, pkW1d[l], e1b, xd, NN);       // xd1 (+em1_b)
        k_edge_upd<<<ge, 256, 0, stream>>>(out_ea, W1e, e2W, e2b, xs, xd, srcp, dstp, NE);
    }
}

// Round 4
// 1545.713 us; speedup vs baseline: 8.3405x; 1.6256x over previous
//
#include <hip/hip_runtime.h>
#include <math.h>

#define NN  50000
#define NE  400000
#define NTE 50000
#define FIN 64
#define EDIM 32
#define HD  128
#define NL  2
#define SCAN_B ((NN + 255) / 256)

typedef __attribute__((ext_vector_type(8))) short bf16x8;
typedef __attribute__((ext_vector_type(4))) float f32x4;

static __device__ __forceinline__ unsigned short f2bf(float f) {
    unsigned u = __float_as_uint(f);
    unsigned r = (u + 0x7fffu + ((u >> 16) & 1u)) >> 16;
    return (unsigned short)r;
}

static __device__ __forceinline__ bf16x8 load_a8(const float* p, bool ok) {
    bf16x8 a = {};
    if (ok) {
        const float4 v0 = *(const float4*)(p);
        const float4 v1 = *(const float4*)(p + 4);
        a[0] = (short)f2bf(v0.x); a[1] = (short)f2bf(v0.y);
        a[2] = (short)f2bf(v0.z); a[3] = (short)f2bf(v0.w);
        a[4] = (short)f2bf(v1.x); a[5] = (short)f2bf(v1.y);
        a[6] = (short)f2bf(v1.z); a[7] = (short)f2bf(v1.w);
    }
    return a;
}

// ---- pack fp32 W[K][128] into bf16 MFMA B-frag order: [(kb*8+nt)*64+lane][8] k-contig ----
__global__ void __launch_bounds__(256) k_packW(const float* __restrict__ W,
        unsigned short* __restrict__ out, int K)
{
    const int tid = blockIdx.x * 256 + threadIdx.x;
    const int total = (K / 32) * 512;
    if (tid >= total) return;
    const int lane = tid & 63, nt = (tid >> 6) & 7, kb = tid >> 9;
    const int k0 = kb * 32 + (lane >> 4) * 8;
    const int col = nt * 16 + (lane & 15);
    bf16x8 v;
    #pragma unroll
    for (int j = 0; j < 8; ++j)
        v[j] = (short)f2bf(W[(size_t)(k0 + j) * HD + col]);
    *(bf16x8*)(out + (size_t)tid * 8) = v;
}

// ---- MFMA GEMM: C[M x 128] = A[M x KB*32] @ Wpk (+bias). A fp32. In-place safe. ----
template<int KB>
__global__ void __launch_bounds__(256) k_gemm_mfma(const float* A,
        const unsigned short* __restrict__ Wpk, const float* __restrict__ bias,
        float* C, int M)
{
    const int t = threadIdx.x, w = t >> 6, l = t & 63;
    const int row0b = blockIdx.x * 64;
    const int row0 = row0b + w * 16;
    const int ar = row0 + (l & 15);
    const bool aok = ar < M;
    const int kq = (l >> 4) * 8;
    const int K = KB * 32;
    f32x4 acc[8] = {};
    #pragma unroll
    for (int kb = 0; kb < KB; ++kb) {
        const bf16x8 a = load_a8(A + (size_t)ar * K + kb * 32 + kq, aok);
        #pragma unroll
        for (int nt = 0; nt < 8; ++nt) {
            const bf16x8 b = *(const bf16x8*)(Wpk + (((size_t)(kb * 8 + nt) * 64 + l) << 3));
            acc[nt] = __builtin_amdgcn_mfma_f32_16x16x32_bf16(a, b, acc[nt], 0, 0, 0);
        }
    }
    #pragma unroll
    for (int nt = 0; nt < 8; ++nt) {
        const int col = nt * 16 + (l & 15);
        const float bv = bias ? bias[col] : 0.f;
        #pragma unroll
        for (int r = 0; r < 4; ++r) {
            const int orow = row0 + (l >> 4) * 4 + r;
            if (orow < M) C[(size_t)orow * HD + col] = acc[nt][r] + bv;
        }
    }
}

// ---- MFMA post: out = [x|agg] @ PW with amp/att row scaling ----
__global__ void __launch_bounds__(256) k_post_mfma(const float* __restrict__ x,
        const float* __restrict__ agg, const int* __restrict__ cnt,
        const float* __restrict__ stats, const unsigned short* __restrict__ PWpk,
        const float* __restrict__ pb, float* __restrict__ outb, int M)
{
    __shared__ float s_amp[64], s_att[64];
    const int t = threadIdx.x;
    const int row0b = blockIdx.x * 64;
    if (t < 64) {
        const int n = row0b + t;
        const float cf = (n < M) ? (float)cnt[n] : 1.f;
        const float avg = stats[0] * (1.f / (float)NN);
        const float lg = logf(fmaxf(cf, 1.f) + 1.f);
        s_amp[t] = lg / avg;
        s_att[t] = avg / lg;
    }
    __syncthreads();
    const int w = t >> 6, l = t & 63;
    const int row0 = row0b + w * 16;
    const int ar = row0 + (l & 15);
    const bool aok = ar < M;
    const int kq = (l >> 4) * 8;
    f32x4 aA[8] = {}, aB[8] = {}, aC[8] = {};

    #pragma unroll
    for (int kb = 0; kb < 4; ++kb) {
        const bf16x8 a = load_a8(x + (size_t)ar * HD + kb * 32 + kq, aok);
        #pragma unroll
        for (int nt = 0; nt < 8; ++nt) {
            const bf16x8 b = *(const bf16x8*)(PWpk + (((size_t)(kb * 8 + nt) * 64 + l) << 3));
            aA[nt] = __builtin_amdgcn_mfma_f32_16x16x32_bf16(a, b, aA[nt], 0, 0, 0);
        }
    }
    for (int jb = 0; jb < 4; ++jb) {
        #pragma unroll
        for (int k2 = 0; k2 < 4; ++k2) {
            const bf16x8 a = load_a8(agg + (size_t)ar * 512 + jb * 128 + k2 * 32 + kq, aok);
            const int kb1 = 4  + jb * 4 + k2;
            const int kb2 = 20 + jb * 4 + k2;
            const int kb3 = 36 + jb * 4 + k2;
            #pragma unroll
            for (int nt = 0; nt < 8; ++nt) {
                const bf16x8 b1 = *(const bf16x8*)(PWpk + (((size_t)(kb1 * 8 + nt) * 64 + l) << 3));
                const bf16x8 b2 = *(const bf16x8*)(PWpk + (((size_t)(kb2 * 8 + nt) * 64 + l) << 3));
                const bf16x8 b3 = *(const bf16x8*)(PWpk + (((size_t)(kb3 * 8 + nt) * 64 + l) << 3));
                aA[nt] = __builtin_amdgcn_mfma_f32_16x16x32_bf16(a, b1, aA[nt], 0, 0, 0);
                aB[nt] = __builtin_amdgcn_mfma_f32_16x16x32_bf16(a, b2, aB[nt], 0, 0, 0);
                aC[nt] = __builtin_amdgcn_mfma_f32_16x16x32_bf16(a, b3, aC[nt], 0, 0, 0);
            }
        }
    }
    #pragma unroll
    for (int nt = 0; nt < 8; ++nt) {
        const int col = nt * 16 + (l & 15);
        const float bv = pb[col];
        #pragma unroll
        for (int r = 0; r < 4; ++r) {
            const int lr = w * 16 + (l >> 4) * 4 + r;
            const int orow = row0b + lr;
            if (orow < M)
                outb[(size_t)orow * HD + col] =
                    aA[nt][r] + s_amp[lr] * aB[nt][r] + s_att[lr] * aC[nt][r] + bv;
        }
    }
}

// ---- degree count ----
__global__ void __launch_bounds__(256) k_count(const int* __restrict__ d, int* __restrict__ cnt, int E)
{
    const int e = blockIdx.x * 256 + threadIdx.x;
    if (e < E) atomicAdd(&cnt[d[e]], 1);
}

// ---- mean(log(cnt+1)) numerator ----
__global__ void __launch_bounds__(256) k_avglog(const int* __restrict__ cnt, float* __restrict__ stats)
{
    float s = 0.f;
    for (int n = blockIdx.x * 256 + threadIdx.x; n < NN; n += gridDim.x * 256)
        s += logf((float)cnt[n] + 1.f);
    #pragma unroll
    for (int off = 32; off > 0; off >>= 1) s += __shfl_down(s, off);
    __shared__ float ls[4];
    if ((threadIdx.x & 63) == 0) ls[threadIdx.x >> 6] = s;
    __syncthreads();
    if (threadIdx.x == 0) unsafeAtomicAdd(stats, ls[0] + ls[1] + ls[2] + ls[3]);
}

// ---- CSR build: block inclusive scan ----
__global__ void __launch_bounds__(256) k_scan_block(const int* __restrict__ cnt,
        int* __restrict__ incl, int* __restrict__ part)
{
    __shared__ int s[256];
    const int t = threadIdx.x;
    const int i = blockIdx.x * 256 + t;
    const int v = (i < NN) ? cnt[i] : 0;
    s[t] = v;
    __syncthreads();
    #pragma unroll
    for (int off = 1; off < 256; off <<= 1) {
        const int x = (t >= off) ? s[t - off] : 0;
        __syncthreads();
        s[t] += x;
        __syncthreads();
    }
    if (i < NN) incl[i] = s[t];
    if (t == 255) part[blockIdx.x] = s[255];
}

__global__ void __launch_bounds__(256) k_scan_part(const int* __restrict__ part,
        int* __restrict__ poff, int np)
{
    __shared__ int s[256];
    const int t = threadIdx.x;
    const int v = (t < np) ? part[t] : 0;
    s[t] = v;
    __syncthreads();
    #pragma unroll
    for (int off = 1; off < 256; off <<= 1) {
        const int x = (t >= off) ? s[t - off] : 0;
        __syncthreads();
        s[t] += x;
        __syncthreads();
    }
    poff[t] = s[t] - v;  // exclusive
}

__global__ void __launch_bounds__(256) k_scan_add(const int* __restrict__ incl,
        const int* __restrict__ cnt, const int* __restrict__ poff,
        int* __restrict__ row_start, int* __restrict__ cursor)
{
    const int i = blockIdx.x * 256 + threadIdx.x;
    if (i < NN) {
        const int excl = incl[i] - cnt[i] + poff[blockIdx.x];
        row_start[i] = excl;
        cursor[i] = excl;
    }
    if (i == 0) row_start[NN] = NE;
}

__global__ void __launch_bounds__(256) k_scatter(const int* __restrict__ dstp,
        int* cursor, int* __restrict__ sppos)
{
    const int e = blockIdx.x * 256 + threadIdx.x;
    if (e < NE) sppos[e] = atomicAdd(&cursor[dstp[e]], 1);
}

// ---- MFMA msg: m = ea@We + xd[dst] + xs[src]; row-scatter to mbuf[sppos] ----
__global__ void __launch_bounds__(256) k_msg_mfma(const float* __restrict__ ea,
        const unsigned short* __restrict__ Wepk, const float* __restrict__ xd,
        const float* __restrict__ xs, const int* __restrict__ srcp,
        const int* __restrict__ dstp, const int* __restrict__ sppos,
        float* __restrict__ mbuf, int E)
{
    __shared__ int s_src[64], s_dst[64], s_sp[64];
    const int t = threadIdx.x, w = t >> 6, l = t & 63;
    const int row0b = blockIdx.x * 64;
    if (t < 64) {
        const int e = row0b + t;
        s_src[t] = (e < E) ? srcp[e] : 0;
        s_dst[t] = (e < E) ? dstp[e] : 0;
        s_sp[t]  = (e < E) ? sppos[e] : 0;
    }
    __syncthreads();
    const int row0 = row0b + w * 16;
    const int ar = row0 + (l & 15);
    const bool aok = ar < E;
    const int kq = (l >> 4) * 8;
    f32x4 acc[8] = {};
    #pragma unroll
    for (int kb = 0; kb < 4; ++kb) {
        const bf16x8 a = load_a8(ea + (size_t)ar * HD + kb * 32 + kq, aok);
        #pragma unroll
        for (int nt = 0; nt < 8; ++nt) {
            const bf16x8 b = *(const bf16x8*)(Wepk + (((size_t)(kb * 8 + nt) * 64 + l) << 3));
            acc[nt] = __builtin_amdgcn_mfma_f32_16x16x32_bf16(a, b, acc[nt], 0, 0, 0);
        }
    }
    const int colb = l & 15;
    #pragma unroll
    for (int r = 0; r < 4; ++r) {
        const int lr = w * 16 + (l >> 4) * 4 + r;
        const int e = row0b + lr;
        if (e >= E) continue;
        const int dn = s_dst[lr], sn = s_src[lr], sp = s_sp[lr];
        const float* pd = xd + (size_t)dn * HD + colb;
        const float* ps = xs + (size_t)sn * HD + colb;
        float* pm = mbuf + (size_t)sp * HD + colb;
        #pragma unroll
        for (int nt = 0; nt < 8; ++nt)
            pm[nt * 16] = acc[nt][r] + pd[nt * 16] + ps[nt * 16];
    }
}

// ---- CSR aggregation: one wave per node; agg[n] = [mean | mn | mx | std] ----
__global__ void __launch_bounds__(256) k_agg(const float* __restrict__ mbuf,
        const int* __restrict__ rs, float* __restrict__ agg)
{
    const int n = blockIdx.x * 4 + (threadIdx.x >> 6);
    if (n >= NN) return;
    const int lane = threadIdx.x & 63;
    const int c = lane * 2;
    const int s = rs[n], e = rs[n + 1];
    float s0=0.f, s1=0.f, q0=0.f, q1=0.f;
    float mn0=INFINITY, mn1=INFINITY, mx0=-INFINITY, mx1=-INFINITY;
    for (int i = s; i < e; ++i) {
        const float2 v = *(const float2*)(mbuf + (size_t)i * HD + c);
        s0 += v.x; s1 += v.y;
        q0 += v.x * v.x; q1 += v.y * v.y;
        mn0 = fminf(mn0, v.x); mn1 = fminf(mn1, v.y);
        mx0 = fmaxf(mx0, v.x); mx1 = fmaxf(mx1, v.y);
    }
    const int deg = e - s;
    const float inv = 1.f / (float)(deg > 1 ? deg : 1);
    const float m0 = s0 * inv, m1 = s1 * inv;
    const float sd0 = sqrtf(fmaxf(q0 * inv - m0 * m0, 0.f) + 1e-5f);
    const float sd1 = sqrtf(fmaxf(q1 * inv - m1 * m1, 0.f) + 1e-5f);
    const bool has = deg > 0;
    float* a = agg + (size_t)n * 512 + c;
    *(float2*)(a)       = make_float2(m0, m1);
    *(float2*)(a + 128) = has ? make_float2(mn0, mn1) : make_float2(0.f, 0.f);
    *(float2*)(a + 256) = has ? make_float2(mx0, mx1) : make_float2(0.f, 0.f);
    *(float2*)(a + 384) = make_float2(sd0, sd1);
}

// ---- BN column sums ----
__global__ void __launch_bounds__(256) k_bnstats(const float* __restrict__ ob,
        float* __restrict__ bs, float* __restrict__ bq, int M)
{
    const int c = threadIdx.x & 127;
    const int gsub = threadIdx.x >> 7;
    float s = 0.f, qq = 0.f;
    for (int rr = blockIdx.x * 2 + gsub; rr < M; rr += gridDim.x * 2) {
        const float v = ob[(size_t)rr * HD + c];
        s += v; qq += v * v;
    }
    __shared__ float ls[2][HD], lq[2][HD];
    ls[gsub][c] = s; lq[gsub][c] = qq;
    __syncthreads();
    if (gsub == 0) {
        unsafeAtomicAdd(&bs[c], ls[0][c] + ls[1][c]);
        unsafeAtomicAdd(&bq[c], lq[0][c] + lq[1][c]);
    }
}

// ---- x = (x + relu(bn(out)))/2 ----
__global__ void __launch_bounds__(256) k_xupdate(float* x, const float* __restrict__ ob,
        const float* __restrict__ bs, const float* __restrict__ bq,
        const float* __restrict__ g, const float* __restrict__ bb)
{
    const int i = blockIdx.x * 256 + threadIdx.x;
    const int c0 = (i & 31) * 4;
    const float4 ov = ((const float4*)ob)[i];
    const float4 xv = ((const float4*)x)[i];
    const float o[4]  = {ov.x, ov.y, ov.z, ov.w};
    const float xo[4] = {xv.x, xv.y, xv.z, xv.w};
    float res[4];
    #pragma unroll
    for (int j = 0; j < 4; ++j) {
        const int c = c0 + j;
        const float mu  = bs[c] * (1.f / (float)NN);
        const float var = bq[c] * (1.f / (float)NN) - mu * mu;
        const float bn  = g[c] * (o[j] - mu) * rsqrtf(var + 1e-5f) + bb[c];
        res[j] = (xo[j] + fmaxf(bn, 0.f)) * 0.5f;
    }
    ((float4*)x)[i] = make_float4(res[0], res[1], res[2], res[3]);
}

// ---- MFMA edge update: hid = relu(ea@W1e + xs1[src] + xd1[dst]); ea += (hid@em2 + e2b)/2 ----
__global__ void __launch_bounds__(256) k_edge_upd_mfma(float* ea,
        const unsigned short* __restrict__ W1epk, const unsigned short* __restrict__ e2pk,
        const float* __restrict__ e2b, const float* __restrict__ xs1,
        const float* __restrict__ xd1, const int* __restrict__ srcp,
        const int* __restrict__ dstp, int E)
{
    __shared__ unsigned short s_hid[64 * 128];  // bf16, 16B-slot XOR swizzled
    __shared__ int s_src[64], s_dst[64];
    const int t = threadIdx.x, w = t >> 6, l = t & 63;
    const int row0b = blockIdx.x * 64;
    if (t < 64) {
        const int e = row0b + t;
        s_src[t] = (e < E) ? srcp[e] : 0;
        s_dst[t] = (e < E) ? dstp[e] : 0;
    }
    __syncthreads();
    const int row0 = row0b + w * 16;
    const int ar = row0 + (l & 15);
    const bool aok = ar < E;
    const int kq = (l >> 4) * 8;
    f32x4 acc[8] = {};
    #pragma unroll
    for (int kb = 0; kb < 4; ++kb) {
        const bf16x8 a = load_a8(ea + (size_t)ar * HD + kb * 32 + kq, aok);
        #pragma unroll
        for (int nt = 0; nt < 8; ++nt) {
            const bf16x8 b = *(const bf16x8*)(W1epk + (((size_t)(kb * 8 + nt) * 64 + l) << 3));
            acc[nt] = __builtin_amdgcn_mfma_f32_16x16x32_bf16(a, b, acc[nt], 0, 0, 0);
        }
    }
    // epilogue1: hid = relu(acc + xs1[sn] + xd1[dn]) -> LDS bf16 (swizzled)
    const int colb = l & 15;
    #pragma unroll
    for (int r = 0; r < 4; ++r) {
        const int lr = w * 16 + (l >> 4) * 4 + r;     // local row 0..63
        const int e = row0b + lr;
        const int sn = s_src[lr], dn = s_dst[lr];
        const float* ps = xs1 + (size_t)sn * HD + colb;
        const float* pd = xd1 + (size_t)dn * HD + colb;
        #pragma unroll
        for (int nt = 0; nt < 8; ++nt) {
            const int col = nt * 16 + colb;
            const float h = (e < E) ? fmaxf(acc[nt][r] + ps[nt * 16] + pd[nt * 16], 0.f) : 0.f;
            const int ba = lr * 256 + ((((col >> 3)) ^ (lr & 7)) << 4) + ((col & 7) << 1);
            *(unsigned short*)((char*)s_hid + ba) = f2bf(h);
        }
    }
    __syncthreads();
    // GEMM2: acc2 = hid @ em2 (A-frags from swizzled LDS, one ds_read_b128 per kb)
    f32x4 acc2[8] = {};
    const int lrow = w * 16 + (l & 15);
    #pragma unroll
    for (int kb = 0; kb < 4; ++kb) {
        const int slot = kb * 4 + (l >> 4);
        const int ba = lrow * 256 + ((slot ^ (lrow & 7)) << 4);
        const bf16x8 a = *(const bf16x8*)((const char*)s_hid + ba);
        #pragma unroll
        for (int nt = 0; nt < 8; ++nt) {
            const bf16x8 b = *(const bf16x8*)(e2pk + (((size_t)(kb * 8 + nt) * 64 + l) << 3));
            acc2[nt] = __builtin_amdgcn_mfma_f32_16x16x32_bf16(a, b, acc2[nt], 0, 0, 0);
        }
    }
    // epilogue2: ea = ea_old + (acc2 + b)/2 at C-fragment positions
    #pragma unroll
    for (int r = 0; r < 4; ++r) {
        const int lr = w * 16 + (l >> 4) * 4 + r;
        const int e = row0b + lr;
        if (e >= E) continue;
        float* pe = ea + (size_t)e * HD + colb;
        #pragma unroll
        for (int nt = 0; nt < 8; ++nt) {
            const int col = nt * 16 + colb;
            pe[nt * 16] = pe[nt * 16] + (acc2[nt][r] + e2b[col]) * 0.5f;
        }
    }
}

extern "C" void kernel_launch(void* const* d_in, const int* in_sizes, int n_in,
                              void* d_out, int out_size, void* d_ws, size_t ws_size,
                              hipStream_t stream)
{
    const float* x0    = (const float*)d_in[0];
    const float* eatr  = (const float*)d_in[1];
    const float* teatr = (const float*)d_in[2];
    const float* nodeW = (const float*)d_in[3];
    const float* nodeb = (const float*)d_in[4];
    const float* edgeW = (const float*)d_in[5];
    const float* edgeb = (const float*)d_in[6];
    const float* preW  = (const float*)d_in[7];
    const float* preb  = (const float*)d_in[8];
    const float* postW = (const float*)d_in[9];
    const float* postb = (const float*)d_in[10];
    const float* linW  = (const float*)d_in[11];
    const float* linb  = (const float*)d_in[12];
    const float* bng   = (const float*)d_in[13];
    const float* bnb   = (const float*)d_in[14];
    const float* em1W  = (const float*)d_in[15];
    const float* em1b  = (const float*)d_in[16];
    const float* em2W  = (const float*)d_in[17];
    const float* em2b  = (const float*)d_in[18];
    const int*   eidx  = (const int*)d_in[19];
    const int* srcp = eidx;
    const int* dstp = eidx + NE;

    float* out_x  = (float*)d_out;
    float* out_ea = out_x + (size_t)NN * HD;
    float* out_te = out_ea + (size_t)NE * HD;

    const size_t NH = (size_t)NN * HD;
    const size_t EH = (size_t)NE * HD;
    float* xd   = (float*)d_ws;
    float* xs   = xd + NH;
    float* agg  = xs + NH;          // [NN][512]
    float* outb = agg + 4 * NH;
    float* mbuf = outb + NH;        // [NE][128] messages in CSR order
    float* stats = mbuf + EH;
    int*   cnt      = (int*)(stats + 512);
    int*   row_start = cnt + NN;    // NN+1
    int*   cursor   = row_start + NN + 1;
    int*   tmpincl  = cursor + NN;
    int*   part     = tmpincl + NN;     // 256
    int*   poff     = part + 256;       // 256
    int*   sppos    = poff + 256;       // NE
    unsigned short* pkbase = (unsigned short*)(((uintptr_t)(sppos + NE) + 15) & ~(uintptr_t)15);
    const size_t PK_PW = (size_t)52 * 512 * 8;   // K=1664
    const size_t PK_SQ = (size_t)4  * 512 * 8;   // K=128
    const size_t PK_K64 = (size_t)2 * 512 * 8;   // K=64
    const size_t PK_K32 = (size_t)1 * 512 * 8;   // K=32
    unsigned short* pkPW[NL], *pkWd[NL], *pkWs[NL], *pkLin[NL], *pkW1s[NL], *pkW1d[NL];
    unsigned short* pkWe[NL], *pkW1e[NL], *pkE2[NL];
    unsigned short *pkNode, *pkEdge;
    {
        unsigned short* p = pkbase;
        for (int l = 0; l < NL; ++l) { pkPW[l] = p; p += PK_PW; }
        for (int l = 0; l < NL; ++l) {
            pkWd[l]  = p; p += PK_SQ;
            pkWs[l]  = p; p += PK_SQ;
            pkLin[l] = p; p += PK_SQ;
            pkW1s[l] = p; p += PK_SQ;
            pkW1d[l] = p; p += PK_SQ;
            pkWe[l]  = p; p += PK_SQ;
            pkW1e[l] = p; p += PK_SQ;
            pkE2[l]  = p; p += PK_SQ;
        }
        pkNode = p; p += PK_K64;
        pkEdge = p; p += PK_K32;
    }

    hipMemsetAsync(cnt, 0, NN * sizeof(int), stream);
    hipMemsetAsync(stats, 0, 512 * sizeof(float), stream);

    // pack weights
    for (int l = 0; l < NL; ++l) {
        k_packW<<<104, 256, 0, stream>>>(postW + (size_t)l * 1664 * HD, pkPW[l], 1664);
        k_packW<<<8, 256, 0, stream>>>(preW + (size_t)l * 384 * HD,            pkWd[l],  128);
        k_packW<<<8, 256, 0, stream>>>(preW + (size_t)l * 384 * HD + 128 * HD, pkWs[l],  128);
        k_packW<<<8, 256, 0, stream>>>(preW + (size_t)l * 384 * HD + 256 * HD, pkWe[l],  128);
        k_packW<<<8, 256, 0, stream>>>(linW + (size_t)l * HD * HD,             pkLin[l], 128);
        k_packW<<<8, 256, 0, stream>>>(em1W + (size_t)l * 384 * HD,            pkW1s[l], 128);
        k_packW<<<8, 256, 0, stream>>>(em1W + (size_t)l * 384 * HD + 128 * HD, pkW1d[l], 128);
        k_packW<<<8, 256, 0, stream>>>(em1W + (size_t)l * 384 * HD + 256 * HD, pkW1e[l], 128);
        k_packW<<<8, 256, 0, stream>>>(em2W + (size_t)l * HD * HD,             pkE2[l],  128);
    }
    k_packW<<<4, 256, 0, stream>>>(nodeW, pkNode, 64);
    k_packW<<<2, 256, 0, stream>>>(edgeW, pkEdge, 32);

    // prologue embeddings (MFMA)
    k_gemm_mfma<1><<<(NE + 63) / 64, 256, 0, stream>>>(eatr, pkEdge, edgeb, out_ea, NE);
    k_gemm_mfma<1><<<(NTE + 63) / 64, 256, 0, stream>>>(teatr, pkEdge, edgeb, out_te, NTE);
    k_gemm_mfma<2><<<(NN + 63) / 64, 256, 0, stream>>>(x0, pkNode, nodeb, out_x, NN);

    // CSR build
    k_count<<<(NE + 255) / 256, 256, 0, stream>>>(dstp, cnt, NE);
    k_avglog<<<256, 256, 0, stream>>>(cnt, stats);
    k_scan_block<<<SCAN_B, 256, 0, stream>>>(cnt, tmpincl, part);
    k_scan_part<<<1, 256, 0, stream>>>(part, poff, SCAN_B);
    k_scan_add<<<SCAN_B, 256, 0, stream>>>(tmpincl, cnt, poff, row_start, cursor);
    k_scatter<<<(NE + 255) / 256, 256, 0, stream>>>(dstp, cursor, sppos);

    const int gn = (NN + 63) / 64;
    const int ge = (NE + 63) / 64;

    for (int l = 0; l < NL; ++l) {
        const float* pbl = preb + l * HD;
        const float* pob = postb + l * HD;
        const float* lb  = linb + l * HD;
        const float* g_  = bng + l * HD;
        const float* b_  = bnb + l * HD;
        const float* e1b = em1b + l * HD;
        const float* e2b = em2b + l * HD;

        hipMemsetAsync(stats + 128, 0, 256 * sizeof(float), stream);

        k_gemm_mfma<4><<<gn, 256, 0, stream>>>(out_x, pkWd[l], pbl, xd, NN);
        k_gemm_mfma<4><<<gn, 256, 0, stream>>>(out_x, pkWs[l], nullptr, xs, NN);
        k_msg_mfma<<<ge, 256, 0, stream>>>(out_ea, pkWe[l], xd, xs, srcp, dstp, sppos, mbuf, NE);
        k_agg<<<(NN + 3) / 4, 256, 0, stream>>>(mbuf, row_start, agg);
        k_post_mfma<<<gn, 256, 0, stream>>>(out_x, agg, cnt, stats, pkPW[l], pob, outb, NN);
        k_gemm_mfma<4><<<gn, 256, 0, stream>>>(outb, pkLin[l], lb, outb, NN);
        k_bnstats<<<256, 256, 0, stream>>>(outb, stats + 128, stats + 256, NN);
        k_xupdate<<<NN * 32 / 256, 256, 0, stream>>>(out_x, outb, stats + 128, stats + 256, g_, b_);
        k_gemm_mfma<4><<<gn, 256, 0, stream>>>(out_x, pkW1s[l], nullptr, xs, NN);   // xs1
        k_gemm_mfma<4><<<gn, 256, 0, stream>>>(out_x, pkW1d[l], e1b, xd, NN);       // xd1 (+em1_b)
        k_edge_upd_mfma<<<ge, 256, 0, stream>>>(out_ea, pkW1e[l], pkE2[l], e2b, xs, xd, srcp, dstp, NE);
    }
}